// Round 1
// 5288.743 us; speedup vs baseline: 1.1184x; 1.1184x over previous
//
#include <hip/hip_runtime.h>

#define NB 64      // batch
#define NL 512     // seq len
#define NT 64      // answer len
#define NH 512     // hidden
#define NE 256     // emb dim
#define NW 256     // attention weight dim

typedef __attribute__((ext_vector_type(8))) short bf16x8;
typedef __attribute__((ext_vector_type(4))) float f32x4;
typedef unsigned short u16;
typedef unsigned int u32;
typedef unsigned long long u64;

#define STM 0x4000400040004000ull   // bit14 of each u16 (never set in bf16 of |v|<2)
#define CLRM 0xBFFFBFFFBFFFBFFFull

__device__ __forceinline__ float bf2f(u16 v){
  union { u32 u; float f; } x; x.u = ((u32)v) << 16; return x.f;
}
__device__ __forceinline__ u16 f2bf(float f){
  union { float f; u32 u; } x; x.f = f;
  return (u16)((x.u + 0x7FFFu + ((x.u >> 16) & 1u)) >> 16);
}
__device__ __forceinline__ float sigm(float x){ return 1.f / (1.f + __expf(-x)); }
__device__ __forceinline__ float tanh_(float x){ float e = __expf(2.f * x); return 1.f - 2.f / (e + 1.f); }

// agent-scope load: bypasses L1, reads at the device coherence point
__device__ __forceinline__ u64 ald64(const u64* p){
  return __hip_atomic_load(p, __ATOMIC_RELAXED, __HIP_MEMORY_SCOPE_AGENT);
}
__device__ __forceinline__ u32 ald32(const u32* p){
  return __hip_atomic_load(p, __ATOMIC_RELAXED, __HIP_MEMORY_SCOPE_AGENT);
}
// agent-scope store: pushes to the device coherence point (cross-XCD safe)
__device__ __forceinline__ void ast64(u64* p, u64 v){
  __hip_atomic_store(p, v, __ATOMIC_RELAXED, __HIP_MEMORY_SCOPE_AGENT);
}
// workgroup-scope store: plain store, write-through L1 -> LOCAL L2 only
__device__ __forceinline__ void st64(u64* p, u64 v){
  __hip_atomic_store(p, v, __ATOMIC_RELAXED, __HIP_MEMORY_SCOPE_WORKGROUP);
}
__device__ __forceinline__ bf16x8 mk8(u64 a, u64 b){
  union { u64 q[2]; bf16x8 v; } u; u.q[0] = a; u.q[1] = b; return u.v;
}
__device__ __forceinline__ u32 xcc_id(){
  u32 x;
  asm volatile("s_getreg_b32 %0, hwreg(HW_REG_XCC_ID)" : "=s"(x));
  return x & 7u;
}

// MFMA burn: keeps the matrix pipe of an otherwise-idle CU busy so the DVFS
// governor holds high clocks. Counter evidence (R0): enc runs at ~750 MHz
// effective clock with 32/256 CUs active and sleep-polling waves; the serial
// recurrence pays that 3.2x on its critical path. Zero memory traffic.
__device__ __forceinline__ void burn32(f32x4* bacc, bf16x8 junk){
#pragma unroll
  for(int i = 0; i < 8; ++i)
#pragma unroll
    for(int g = 0; g < 4; ++g)
      bacc[g] = __builtin_amdgcn_mfma_f32_16x16x32_bf16(junk, junk, bacc[g], 0, 0, 0);
}
__device__ __forceinline__ void burn_sink(f32x4* bacc){
  asm volatile("" :: "v"(bacc[0][0]), "v"(bacc[1][0]), "v"(bacc[2][0]), "v"(bacc[3][0]));
}

__global__ void fill_kernel(u32* p, u32 v){
  p[blockIdx.x * 256 + threadIdx.x] = v;
}

// fp32 -> bf16 (round-to-nearest-even)
__global__ void cvt_kernel(const float* __restrict__ src, u16* __restrict__ dst, int n){
  const int i = blockIdx.x * 256 + threadIdx.x;
  if(i < n) dst[i] = f2bf(src[i]);
}

// ---------------------------------------------------------------------------
// Encoder: 256 blocks x 90 KB dyn LDS -> 1 block/CU -> machine-filling grid.
// 32 producer blocks (XCD 0..3, rank 0..7) run the R16 in-XCD ring exchange
// unchanged, but (a) the blend1 fold is REMOVED from the serial loop and
// (b) each h_t is additionally published (agent scope, write-once stamped)
// to hist[t]. The 224 remaining blocks become blend1 workers: poll hist[t],
// compute blend1(t) = h_t @ W1^T + b1, write bl, and MFMA-burn while waiting
// (and after their last task, until hist[NL-1] is stamped) so ALL 256 CUs
// draw power for the entire encoder -> DVFS holds high clocks for the
// latency-bound recurrence.
// ---------------------------------------------------------------------------
__global__ void __launch_bounds__(256, 1) enc_kernel(
    const int* __restrict__ ids, const u16* __restrict__ emb,
    const u16* __restrict__ Wih, const u16* __restrict__ Whh,
    const float* __restrict__ bih, const float* __restrict__ bhh,
    const u16* __restrict__ W1,  const float* __restrict__ b1,
    u16* hroll, u16* hist, u16* bl, u32* cnt)
{
  extern __shared__ u64 hsh[];            // [2][64*33] used; 90 KB reserved
  __shared__ u32 srank;
  __shared__ u32 swid;

  const int lane = threadIdx.x & 63;
  const int wvl  = threadIdx.x >> 6;      // 0..3
  const int col  = lane & 15;
  const int quad = lane >> 4;

  const u32 xcd = xcc_id();
  u32 rank = 0xFFFFFFFFu;
  if(xcd < 4){
    if(threadIdx.x == 0) srank = atomicAdd(&cnt[xcd], 1u);
    __syncthreads();
    rank = srank;
  }

  if(rank >= 8){
    // ------------------------- blend1 worker -------------------------
    if(threadIdx.x == 0) swid = atomicAdd(&cnt[4], 1u);
    __syncthreads();
    const int wid = (int)swid;            // 0..223

    f32x4 bacc[4];
#pragma unroll
    for(int g = 0; g < 4; ++g) bacc[g] = (f32x4){0.f, 0.f, 0.f, 0.f};
    const bf16x8 junk = {0, 0, 0, 0, 0, 0, 0, 0};

    const int ab2 = wvl * 16 + col;       // batch row this lane's wave owns
    for(int t = wid; t < NL; t += 224){
      const u16* ha = hist + (size_t)t * (NB * NH) + (size_t)ab2 * NH + quad * 8;
      // cheap poll (1 u64/lane, last-written piece) with burn overlap
      {
        const u64* p15 = (const u64*)(ha + 32 * 15);
        for(;;){
          const u64 v = ald64(p15);
          burn32(bacc, junk);
          burn32(bacc, junk);
          if((v & STM) == STM) break;
        }
      }
      // full poll: 16 pieces/lane = full row ab2 (all producer waves)
      u64 hw[32];
      for(;;){
        bool ok = true;
#pragma unroll
        for(int i = 0; i < 16; ++i){
          const u64* p = (const u64*)(ha + 32 * i);
          hw[2 * i]     = ald64(p);
          hw[2 * i + 1] = ald64(p + 1);
          ok = ok && ((hw[2 * i] & STM) == STM) && ((hw[2 * i + 1] & STM) == STM);
        }
        if(__ballot(ok) == ~0ull) break;
        __builtin_amdgcn_s_sleep(1);
      }
      bf16x8 af[16];
#pragma unroll
      for(int i = 0; i < 16; ++i) af[i] = mk8(hw[2 * i] & CLRM, hw[2 * i + 1] & CLRM);

      // blend1(t): 16 n-tiles, independent accumulator chains
      f32x4 a2[16];
#pragma unroll
      for(int n = 0; n < 16; ++n) a2[n] = (f32x4){0.f, 0.f, 0.f, 0.f};
      const u16* w1c = W1 + (size_t)col * NH + quad * 8;
#pragma unroll
      for(int i = 0; i < 16; ++i){
#pragma unroll
        for(int n = 0; n < 16; ++n){
          const bf16x8 bf = *(const bf16x8*)(w1c + (size_t)(n * 16) * NH + 32 * i);
          a2[n] = __builtin_amdgcn_mfma_f32_16x16x32_bf16(af[i], bf, a2[n], 0, 0, 0);
        }
      }
#pragma unroll
      for(int n = 0; n < 16; ++n){
        const float bb = b1[n * 16 + col];
#pragma unroll
        for(int r = 0; r < 4; ++r){
          const int b = wvl * 16 + quad * 4 + r;
          bl[((size_t)t * NB + b) * NW + n * 16 + col] = f2bf(a2[n][r] + bb);
        }
      }
    }
    // hold the CU hot until the encoder is fully done (slot NL-1 stamped)
    {
      const u64* dp = (const u64*)(hist + (size_t)(NL - 1) * (NB * NH) + (size_t)lane * NH + 32 * 15);
      for(;;){
        const u64 v = ald64(dp);
        burn32(bacc, junk);
        burn32(bacc, junk);
        if((v & STM) == STM) break;
      }
    }
    burn_sink(bacc);
    return;
  }

  // ------------------------- producer path (R16 core) -------------------------
  const int btile = (int)xcd;
  const int mtile = (int)rank * 4 + wvl;  // 0..31
  const int j  = mtile * 16 + col;        // hidden index within a gate [0,512)
  const int ab = btile * 16 + col;        // A-row (batch) this lane loads

  float bias[4];
  const u16* wx[4];
  bf16x8 whr[16][4];                      // register-resident Whh fragments
#pragma unroll
  for(int g = 0; g < 4; ++g){
    const int row = g * NH + j;           // PyTorch gate order i,f,g,o
    bias[g] = bih[row] + bhh[row];
    wx[g] = Wih + (size_t)row * NE + quad * 8;
    const u16* whp = Whh + (size_t)row * NH + quad * 8;
#pragma unroll
    for(int i = 0; i < 16; ++i)
      whr[i][g] = *(const bf16x8*)(whp + 32 * i);
  }
  const int* idp = ids + ab * NL;         // ids is [B, L]
  float creg[4] = {0.f, 0.f, 0.f, 0.f};   // cell state, lane-owned

  u64 hb[32];                             // h fragment (stamp-cleaned)
  f32x4 acc[4];

  // x-part of t=0
  {
    const u16* xr = emb + (size_t)idp[0] * NE + quad * 8;
#pragma unroll
    for(int g = 0; g < 4; ++g) acc[g] = (f32x4){0.f, 0.f, 0.f, 0.f};
#pragma unroll
    for(int k0 = 0; k0 < NE; k0 += 32){
      const bf16x8 af = *(const bf16x8*)(xr + k0);
#pragma unroll
      for(int g = 0; g < 4; ++g)
        acc[g] = __builtin_amdgcn_mfma_f32_16x16x32_bf16(af, *(const bf16x8*)(wx[g] + k0), acc[g], 0, 0, 0);
    }
  }

  for(int t = 0; t < NL; ++t){
    // h part (hb = h_{t-1}, shared via LDS last iteration) — all-register
    if(t > 0){
#pragma unroll
      for(int i = 0; i < 16; ++i){
        const bf16x8 af = mk8(hb[2 * i], hb[2 * i + 1]);
#pragma unroll
        for(int g = 0; g < 4; ++g)
          acc[g] = __builtin_amdgcn_mfma_f32_16x16x32_bf16(af, whr[i][g], acc[g], 0, 0, 0);
      }
    }
    // epilogue: gates -> c (regs); h_t packed; ring store (local L2, phase
    // stamp) feeds the exchange; hist store (agent scope, fixed stamp) feeds
    // the cross-XCD blend1 workers. Fold is gone from the serial loop.
    const u64 rst = ((t >> 1) & 1) ? STM : 0ull;
    u16* ho = hroll + (t & 1) * (NB * NH);
    u16* hh = hist + (size_t)t * (NB * NH);
#pragma unroll
    for(int r = 0; r < 4; ++r){
      const float gi = acc[0][r] + bias[0];
      const float gf = acc[1][r] + bias[1];
      const float gg = acc[2][r] + bias[2];
      const float go = acc[3][r] + bias[3];
      creg[r] = sigm(gf) * creg[r] + sigm(gi) * tanh_(gg);
      const u32 raw  = (u32)f2bf(sigm(go) * tanh_(creg[r]));
      const u32 pair = raw | (((u32)__shfl_xor((int)raw, 1, 64)) << 16);
      const u32 hi   = (u32)__shfl_xor((int)pair, 2, 64);
      if((col & 3) == 0){
        const int row = btile * 16 + quad * 4 + r;
        const u64 rq = (u64)pair | ((u64)hi << 32);
        st64 ((u64*)(ho + (size_t)row * NH + mtile * 16 + col), rq | rst);
        ast64((u64*)(hh + (size_t)row * NH + mtile * 16 + col), rq | STM);
      }
    }
    if(t + 1 < NL){
      // overlap: x-part of t+1 (latency hidden behind the exchange wait)
      {
        const u16* xr = emb + (size_t)idp[t + 1] * NE + quad * 8;
#pragma unroll
        for(int g = 0; g < 4; ++g) acc[g] = (f32x4){0.f, 0.f, 0.f, 0.f};
#pragma unroll
        for(int k0 = 0; k0 < NE; k0 += 32){
          const bf16x8 af = *(const bf16x8*)(xr + k0);
#pragma unroll
          for(int g = 0; g < 4; ++g)
            acc[g] = __builtin_amdgcn_mfma_f32_16x16x32_bf16(af, *(const bf16x8*)(wx[g] + k0), acc[g], 0, 0, 0);
        }
      }
      // cooperative poll-on-data: wave wvl polls chunks [wvl*4, wvl*4+4);
      // block shares via LDS. No sleep: detection latency is the serial
      // chain, and 32 waves' re-loads are trivial local-L2 traffic.
      {
        const u16* ha = hroll + (t & 1) * (NB * NH) + (size_t)ab * NH + quad * 8;
        const u64 want = ((t >> 1) & 1) ? STM : 0ull;
        const int i0 = wvl * 4;
        u64 tmp[8];
        for(;;){
          bool ok = true;
#pragma unroll
          for(int i = 0; i < 4; ++i){
            const u64* p = (const u64*)(ha + 32 * (i0 + i));
            tmp[2 * i]     = ald64(p);
            tmp[2 * i + 1] = ald64(p + 1);
            ok = ok && ((tmp[2 * i] & STM) == want) && ((tmp[2 * i + 1] & STM) == want);
          }
          if(__ballot(ok) == ~0ull) break;
        }
        u64* hs = &hsh[(t & 1) * (64 * 33) + lane * 33];
#pragma unroll
        for(int i = 0; i < 4; ++i){
          hs[2 * (i0 + i)]     = tmp[2 * i]     & CLRM;
          hs[2 * (i0 + i) + 1] = tmp[2 * i + 1] & CLRM;
        }
        __syncthreads();
#pragma unroll
        for(int i = 0; i < 32; ++i) hb[i] = hs[i];
      }
    }
  }
}

// ---------------------------------------------------------------------------
// Decoder (MERGED): 256 blocks x 256 threads.
// Blocks 0..31: producers — register-resident dWhh, 64 write-once stamped h
// slots over the dead emb region (slot t = h_t); c0 = enc h_511 (hroll slot
// 1), h_{-1} = fp32 h0; cooperative co-poll (no sleep), agent-scope stores.
// Blocks 32..255: 224 attention workers — (t,b) tasks in t-major order,
// burn-poll slot t row b stamps, u = h@W2^T + b2 (f32x4 loads), scores over
// L (bf16x8 loads), log-softmax, write out column (.., b, t).
// ---------------------------------------------------------------------------
__global__ void __launch_bounds__(256, 1) dec_kernel(
    const u16* __restrict__ Whh, const float* __restrict__ bih, const float* __restrict__ bhh,
    const float* __restrict__ W2, const float* __restrict__ b2,
    const float* __restrict__ vt, const float* __restrict__ vtb,
    const u16* __restrict__ bl,  const u16* __restrict__ hroll,
    const float* __restrict__ h0f,
    u16* hdX, float* __restrict__ out)
{
  __shared__ u64 hsh[2][64 * 33];
  __shared__ __align__(16) float h_f[NH];
  __shared__ __align__(16) float u_lds[NW];
  __shared__ __align__(16) float vt_lds[NW];
  __shared__ float red[8];

  const int tid  = threadIdx.x;
  const int lane = tid & 63;
  const int wvl  = tid >> 6;
  const int col  = lane & 15;
  const int quad = lane >> 4;

  if(blockIdx.x < 32){
    // ------------------------- producer path -------------------------
    const int gw   = blockIdx.x * 4 + wvl;
    const int btile = gw >> 5;
    const int mtile = gw & 31;
    const int j  = mtile * 16 + col;
    const int ab = btile * 16 + col;
    float bias[4];
    bf16x8 whr[16][4];
    float creg[4];
#pragma unroll
    for(int g = 0; g < 4; ++g){
      const int row = g * NH + j;
      bias[g] = bih[row] + bhh[row];
      const u16* whp = Whh + (size_t)row * NH + quad * 8;
#pragma unroll
      for(int i = 0; i < 16; ++i)
        whr[i][g] = *(const bf16x8*)(whp + 32 * i);
    }
    // c0 = enc h_511: hroll slot 511&1 == 1, stamp bit set -> mask it
#pragma unroll
    for(int r = 0; r < 4; ++r){
      const int ci = (btile * 16 + quad * 4 + r) * NH + j;
      creg[r] = bf2f((u16)(hroll[(NB * NH) + ci] & 0xBFFFu));
    }

    for(int t = 0; t < NT; ++t){
      f32x4 z = {0.f, 0.f, 0.f, 0.f};
      f32x4 acc[4] = {z, z, z, z};
      if(t == 0){
        // h_{-1} = h0 (fp32, convert in regs)
        const float* hp = h0f + (size_t)ab * NH + quad * 8;
#pragma unroll
        for(int i = 0; i < 16; ++i){
          const f32x4 a0 = *(const f32x4*)(hp + 32 * i);
          const f32x4 a1 = *(const f32x4*)(hp + 32 * i + 4);
          bf16x8 af;
#pragma unroll
          for(int q = 0; q < 4; ++q){ af[q] = (short)f2bf(a0[q]); af[q + 4] = (short)f2bf(a1[q]); }
#pragma unroll
          for(int g = 0; g < 4; ++g)
            acc[g] = __builtin_amdgcn_mfma_f32_16x16x32_bf16(af, whr[i][g], acc[g], 0, 0, 0);
        }
      } else {
        // cooperative poll-on-data: slot t-1 (stamp always 1)
        u64 hb[32];
        {
          const u16* ha = hdX + (size_t)(t - 1) * (NB * NH) + (size_t)ab * NH + quad * 8;
          const int i0 = wvl * 4;
          u64 tmp[8];
          for(;;){
            bool ok = true;
#pragma unroll
            for(int i = 0; i < 4; ++i){
              const u64* p = (const u64*)(ha + 32 * (i0 + i));
              tmp[2 * i]     = ald64(p);
              tmp[2 * i + 1] = ald64(p + 1);
              ok = ok && ((tmp[2 * i] & STM) == STM) && ((tmp[2 * i + 1] & STM) == STM);
            }
            if(__ballot(ok) == ~0ull) break;
          }
          u64* hs = &hsh[t & 1][lane * 33];
#pragma unroll
          for(int i = 0; i < 4; ++i){
            hs[2 * (i0 + i)]     = tmp[2 * i]     & CLRM;
            hs[2 * (i0 + i) + 1] = tmp[2 * i + 1] & CLRM;
          }
          __syncthreads();
#pragma unroll
          for(int i = 0; i < 32; ++i) hb[i] = hs[i];
        }
#pragma unroll
        for(int i = 0; i < 16; ++i){
          const bf16x8 af = mk8(hb[2 * i], hb[2 * i + 1]);
#pragma unroll
          for(int g = 0; g < 4; ++g)
            acc[g] = __builtin_amdgcn_mfma_f32_16x16x32_bf16(af, whr[i][g], acc[g], 0, 0, 0);
        }
      }
      // epilogue: store h_t stamped into slot t (agent scope: cross-XCD)
      u16* hn = hdX + (size_t)t * (NB * NH);
#pragma unroll
      for(int r = 0; r < 4; ++r){
        const float gi = acc[0][r] + bias[0];
        const float gf = acc[1][r] + bias[1];
        const float gg = acc[2][r] + bias[2];
        const float go = acc[3][r] + bias[3];
        creg[r] = sigm(gf) * creg[r] + sigm(gi) * tanh_(gg);
        const u32 stv  = (u32)f2bf(sigm(go) * tanh_(creg[r])) | 0x4000u;
        const u32 pair = stv | (((u32)__shfl_xor((int)stv, 1, 64)) << 16);
        const u32 hi   = (u32)__shfl_xor((int)pair, 2, 64);
        if((col & 3) == 0){
          const int row = btile * 16 + quad * 4 + r;
          ast64((u64*)(hn + (size_t)row * NH + mtile * 16 + col),
                (u64)pair | ((u64)hi << 32));
        }
      }
    }
    return;
  }

  // ------------------------- attention worker path -------------------------
  vt_lds[tid] = vt[tid];
  const float vtbf = vtb[0];
  __syncthreads();

  f32x4 bacc[4];
#pragma unroll
  for(int g = 0; g < 4; ++g) bacc[g] = (f32x4){0.f, 0.f, 0.f, 0.f};
  const bf16x8 junk = {0, 0, 0, 0, 0, 0, 0, 0};

  for(int tk = (int)blockIdx.x - 32; tk < NT * NB; tk += 224){
    const int t = tk >> 6;
    const int b = tk & 63;

    // poll slot t row b (stamped bf16), stage -> fp32 LDS (burn-throttled)
    {
      const u32* hp = (const u32*)(hdX + (size_t)t * (NB * NH) + (size_t)b * NH);
      u32 v;
      for(;;){
        v = ald32(hp + tid);
        burn32(bacc, junk);
        const int ok = ((v & 0x40004000u) == 0x40004000u) ? 1 : 0;
        if(__syncthreads_and(ok)) break;
      }
      h_f[2 * tid]     = bf2f((u16)(v & 0xBFFFu));
      h_f[2 * tid + 1] = bf2f((u16)((v >> 16) & 0xBFFFu));
    }
    __syncthreads();

    // u[n] = b2[n] + h . W2[n,:]   (h broadcast from LDS, f32x4 loads)
    {
      const float* w2r = W2 + (size_t)tid * NH;
      float s = b2[tid];
#pragma unroll 4
      for(int k = 0; k < NH; k += 4){
        const f32x4 hv = *(const f32x4*)(&h_f[k]);
        const f32x4 wv = *(const f32x4*)(w2r + k);
        s += hv[0] * wv[0] + hv[1] * wv[1] + hv[2] * wv[2] + hv[3] * wv[3];
      }
      u_lds[tid] = s;
    }
    __syncthreads();

    // scores for l = tid and l = tid+256 (bf16x8 row loads)
    float a0, a1;
#pragma unroll
    for(int e = 0; e < 2; ++e){
      const int l = tid + e * 256;
      const u16* br = bl + (size_t)(l * NB + b) * NW;
      float p = 0.f;
#pragma unroll 2
      for(int w0 = 0; w0 < NW; w0 += 8){
        const bf16x8 bv = *(const bf16x8*)(br + w0);
#pragma unroll
        for(int q = 0; q < 8; ++q)
          p += vt_lds[w0 + q] * tanh_(bf2f((u16)bv[q]) + u_lds[w0 + q]);
      }
      if(e == 0) a0 = p + vtbf; else a1 = p + vtbf;
    }

    // log-softmax over L = 512 (2 values per thread, block-wide reduction)
    float mx = fmaxf(a0, a1);
#pragma unroll
    for(int off = 32; off > 0; off >>= 1) mx = fmaxf(mx, __shfl_xor(mx, off, 64));
    if(lane == 0) red[wvl] = mx;
    __syncthreads();
    mx = fmaxf(fmaxf(red[0], red[1]), fmaxf(red[2], red[3]));
    float es = __expf(a0 - mx) + __expf(a1 - mx);
#pragma unroll
    for(int off = 32; off > 0; off >>= 1) es += __shfl_xor(es, off, 64);
    if(lane == 0) red[4 + wvl] = es;
    __syncthreads();
    const float lse = mx + logf(red[4] + red[5] + red[6] + red[7]);
    out[((size_t)tid * NB + b) * NT + t]         = a0 - lse;
    out[((size_t)(tid + 256) * NB + b) * NT + t] = a1 - lse;
    __syncthreads();
  }
  burn_sink(bacc);
}

// ---------------------------------------------------------------------------
extern "C" void kernel_launch(void* const* d_in, const int* in_sizes, int n_in,
                              void* d_out, int out_size, void* d_ws, size_t ws_size,
                              hipStream_t stream)
{
  (void)in_sizes; (void)n_in; (void)out_size; (void)ws_size;
  const int*   ids  = (const int*)d_in[0];
  const float* emb  = (const float*)d_in[1];
  const float* eWih = (const float*)d_in[2];
  const float* eWhh = (const float*)d_in[3];
  const float* ebih = (const float*)d_in[4];
  const float* ebhh = (const float*)d_in[5];
  /* d_in[6] = dec_Wih: unused (decoder input is identically zero) */
  const float* dWhh = (const float*)d_in[7];
  const float* dbih = (const float*)d_in[8];
  const float* dbhh = (const float*)d_in[9];
  const float* W1   = (const float*)d_in[10];
  const float* b1   = (const float*)d_in[11];
  const float* W2   = (const float*)d_in[12];
  const float* b2   = (const float*)d_in[13];
  const float* vt   = (const float*)d_in[14];
  const float* vtb  = (const float*)d_in[15];
  const float* h0   = (const float*)d_in[16];

  // workspace: ~58.3 MiB. X is bf16-emb during enc, then the decoder's 64
  // write-once h slots. hist is the full encoder state history (write-once
  // stamped) feeding the 224 cross-XCD blend1 worker blocks.
  char* ws = (char*)d_ws;
  u16* bl     = (u16*)ws; ws += (size_t)NL * NB * NW * 2;    // blend1 bf16  16.78 MB
  u16* hroll  = (u16*)ws; ws += (size_t)2 * NB * NH * 2;     // enc h ring   0.13 MB
  u16* X      = (u16*)ws; ws += (size_t)10000 * NE * 2;      // emb_b / hdec 5.12 MB
  u16* eWih_b = (u16*)ws; ws += (size_t)4 * NH * NE * 2;     // 1.05 MB
  u16* eWhh_b = (u16*)ws; ws += (size_t)4 * NH * NH * 2;     // 2.10 MB
  u16* dWhh_b = (u16*)ws; ws += (size_t)4 * NH * NH * 2;     // 2.10 MB
  u16* W1_b   = (u16*)ws; ws += (size_t)NW * NH * 2;         // 0.26 MB
  u16* hist   = (u16*)ws; ws += (size_t)NL * NB * NH * 2;    // enc states  33.55 MB
  u32* cnt    = (u32*)ws; ws += 1024;                        // rank/worker counters

  // enc ring slots pre-filled with stamp-1 pattern; hist zeroed (stamp clear);
  // rank counters zeroed
  hipLaunchKernelGGL(fill_kernel, dim3((2 * NB * NH / 2) / 256), dim3(256), 0, stream,
                     (u32*)hroll, 0x40004000u);
  hipLaunchKernelGGL(fill_kernel, dim3(((size_t)NL * NB * NH / 2) / 256), dim3(256), 0, stream,
                     (u32*)hist, 0u);
  hipLaunchKernelGGL(fill_kernel, dim3(1), dim3(256), 0, stream, cnt, 0u);
  hipLaunchKernelGGL(cvt_kernel, dim3(10000), dim3(256), 0, stream, emb,  X,      10000 * NE);
  hipLaunchKernelGGL(cvt_kernel, dim3(2048),  dim3(256), 0, stream, eWih, eWih_b, 4 * NH * NE);
  hipLaunchKernelGGL(cvt_kernel, dim3(4096),  dim3(256), 0, stream, eWhh, eWhh_b, 4 * NH * NH);
  hipLaunchKernelGGL(cvt_kernel, dim3(4096),  dim3(256), 0, stream, dWhh, dWhh_b, 4 * NH * NH);
  hipLaunchKernelGGL(cvt_kernel, dim3(512),   dim3(256), 0, stream, W1,   W1_b,   NW * NH);

  // 90 KB dynamic LDS -> 1 block/CU -> machine-filling grid: 32 producer
  // blocks (8 per XCD 0..3 by capacity pigeonhole) + 224 blend1/burn workers
  hipLaunchKernelGGL(enc_kernel, dim3(256), dim3(256), 92160, stream,
                     ids, X, eWih_b, eWhh_b, ebih, ebhh, W1_b, b1, hroll, hist, bl, cnt);
  hipLaunchKernelGGL(dec_kernel, dim3(256), dim3(256), 0, stream,
                     dWhh_b, dbih, dbhh, W2, b2, vt, vtb, bl, hroll, h0, X,
                     (float*)d_out);
}

// Round 2
// 4397.155 us; speedup vs baseline: 1.3452x; 1.2028x over previous
//
#include <hip/hip_runtime.h>

#define NB 64      // batch
#define NL 512     // seq len
#define NT 64      // answer len
#define NH 512     // hidden
#define NE 256     // emb dim
#define NW 256     // attention weight dim
#define NBNH (NB * NH)
#define RS 16      // h-ring depth (slots); phase stamp = (t>>4)&1

typedef __attribute__((ext_vector_type(8))) short bf16x8;
typedef __attribute__((ext_vector_type(4))) float f32x4;
typedef unsigned short u16;
typedef unsigned int u32;
typedef unsigned long long u64;

#define STM 0x4000400040004000ull   // bit14 of each u16 (never set in bf16 of |v|<2)
#define CLRM 0xBFFFBFFFBFFFBFFFull

__device__ __forceinline__ float bf2f(u16 v){
  union { u32 u; float f; } x; x.u = ((u32)v) << 16; return x.f;
}
__device__ __forceinline__ u16 f2bf(float f){
  union { float f; u32 u; } x; x.f = f;
  return (u16)((x.u + 0x7FFFu + ((x.u >> 16) & 1u)) >> 16);
}
__device__ __forceinline__ float sigm(float x){ return 1.f / (1.f + __expf(-x)); }
__device__ __forceinline__ float tanh_(float x){ float e = __expf(2.f * x); return 1.f - 2.f / (e + 1.f); }

// agent-scope load: bypasses L1; hits the local-XCD L2 for locally-written
// lines (R0 FETCH evidence: ring polls produced no L2-miss traffic)
__device__ __forceinline__ u64 ald64(const u64* p){
  return __hip_atomic_load(p, __ATOMIC_RELAXED, __HIP_MEMORY_SCOPE_AGENT);
}
__device__ __forceinline__ u32 ald32(const u32* p){
  return __hip_atomic_load(p, __ATOMIC_RELAXED, __HIP_MEMORY_SCOPE_AGENT);
}
// agent-scope store: pushes to the device coherence point (cross-XCD safe)
__device__ __forceinline__ void ast64(u64* p, u64 v){
  __hip_atomic_store(p, v, __ATOMIC_RELAXED, __HIP_MEMORY_SCOPE_AGENT);
}
// workgroup-scope store: plain store, write-through L1 -> LOCAL L2 only
__device__ __forceinline__ void st64(u64* p, u64 v){
  __hip_atomic_store(p, v, __ATOMIC_RELAXED, __HIP_MEMORY_SCOPE_WORKGROUP);
}
__device__ __forceinline__ bf16x8 mk8(u64 a, u64 b){
  union { u64 q[2]; bf16x8 v; } u; u.q[0] = a; u.q[1] = b; return u.v;
}
__device__ __forceinline__ u32 xcc_id(){
  u32 x;
  asm volatile("s_getreg_b32 %0, hwreg(HW_REG_XCC_ID)" : "=s"(x));
  return x & 7u;
}
// MFMA burn while polling (dec attention workers only — R1 parity there)
__device__ __forceinline__ void burn32(f32x4* bacc, bf16x8 junk){
#pragma unroll
  for(int i = 0; i < 8; ++i)
#pragma unroll
    for(int g = 0; g < 4; ++g)
      bacc[g] = __builtin_amdgcn_mfma_f32_16x16x32_bf16(junk, junk, bacc[g], 0, 0, 0);
}
__device__ __forceinline__ void burn_sink(f32x4* bacc){
  asm volatile("" :: "v"(bacc[0][0]), "v"(bacc[1][0]), "v"(bacc[2][0]), "v"(bacc[3][0]));
}

__global__ void fill_kernel(u32* p, u32 v){
  p[blockIdx.x * 256 + threadIdx.x] = v;
}

// fp32 -> bf16 (round-to-nearest-even)
__global__ void cvt_kernel(const float* __restrict__ src, u16* __restrict__ dst, int n){
  const int i = blockIdx.x * 256 + threadIdx.x;
  if(i < n) dst[i] = f2bf(src[i]);
}

// ---------------------------------------------------------------------------
// Encoder, K-SPLIT: 256 blocks x 90 KB dyn LDS -> 1 block/CU (bijection) ->
// every XCD hosts exactly 32 blocks. XCD 0..3: ranks 0..15 = producers
// (2 mtiles x 2 K-halves per block), ranks 16..31 = blend1 workers (one
// 16-col W1 tile each). XCD 4..7 exit.
//   - wave task = (mtile, khalf): whr[8][4] = 128 VGPR -> total ~230 VGPR,
//     fits in 256 => no demotion of the weight fragments (R1: needed ~370,
//     got 256 => per-step reload traffic on the serial chain).
//   - wave pair (khalf 0/1) merges partial acc via 16-float LDS + 1 barrier;
//     lower wave does gates/c/h + the ONLY store on the chain: 4x st64 to
//     the 16-deep local-L2 ring (cheap acks -> no vmcnt convoy).
//   - each wave polls its own K-half straight from the ring (no LDS hop).
//   - blend1 + bl stores moved to the 16 local worker blocks; hist deleted.
// ---------------------------------------------------------------------------
__global__ void __launch_bounds__(256, 1) enc_kernel(
    const int* __restrict__ ids, const u16* __restrict__ emb,
    const u16* __restrict__ Wih, const u16* __restrict__ Whh,
    const float* __restrict__ bih, const float* __restrict__ bhh,
    const u16* __restrict__ W1,  const float* __restrict__ b1,
    u16* hroll, u16* bl, u32* cnt)
{
  extern __shared__ char dynsm[];         // 90 KB reserved (1 block/CU forcing)
  f32x4* pacc = (f32x4*)dynsm;            // [2 buf][2 pair][4 gate][64 lane]
  __shared__ u32 srank;

  const int lane = threadIdx.x & 63;
  const int wvl  = threadIdx.x >> 6;      // 0..3
  const int col  = lane & 15;
  const int quad = lane >> 4;

  const u32 xcd = xcc_id();
  if(xcd >= 4) return;
  if(threadIdx.x == 0) srank = atomicAdd(&cnt[xcd], 1u);
  __syncthreads();
  const u32 rank = srank;
  const int btile = (int)xcd;

  if(rank >= 16){
    // ---------------- blend1 worker: cols [ (rank-16)*16, +16 ) ----------------
    if(rank >= 32 || wvl != 0) return;    // 1 wave per worker block
    const int n1 = ((int)rank - 16) * 16 + col;
    bf16x8 w1f[16];                       // W1 row n1, register-cached
    const u16* w1p = W1 + (size_t)n1 * NH + quad * 8;
#pragma unroll
    for(int i = 0; i < 16; ++i) w1f[i] = *(const bf16x8*)(w1p + 32 * i);
    const float b1f = b1[n1];
    const int arow = btile * 16 + col;    // h row this lane holds as A-frag

    for(int t = 0; t < NL; ++t){
      const u16* ha = hroll + (size_t)(t & (RS - 1)) * NBNH + (size_t)arow * NH + quad * 8;
      const u64 want = ((t >> 4) & 1) ? STM : 0ull;
      u64 hw[32];
      for(;;){
        bool ok = true;
#pragma unroll
        for(int i = 0; i < 16; ++i){
          const u64* p = (const u64*)(ha + 32 * i);
          hw[2 * i]     = ald64(p);
          hw[2 * i + 1] = ald64(p + 1);
          ok = ok && ((hw[2 * i] & STM) == want) && ((hw[2 * i + 1] & STM) == want);
        }
        if(__ballot(ok) == ~0ull) break;
        __builtin_amdgcn_s_sleep(1);      // workers have slack; spare the L2
      }
      f32x4 a2 = {0.f, 0.f, 0.f, 0.f};
#pragma unroll
      for(int i = 0; i < 16; ++i)
        a2 = __builtin_amdgcn_mfma_f32_16x16x32_bf16(
               mk8(hw[2 * i] & CLRM, hw[2 * i + 1] & CLRM), w1f[i], a2, 0, 0, 0);
#pragma unroll
      for(int r = 0; r < 4; ++r){
        const int b = btile * 16 + quad * 4 + r;
        bl[((size_t)t * NB + b) * NW + n1] = f2bf(a2[r] + b1f);
      }
    }
    return;
  }

  // ------------------------------ producer ------------------------------
  const int mtile  = (int)rank * 2 + (wvl >> 1);   // 0..31
  const int khalf  = wvl & 1;                      // K-half of the recurrence
  const int pairid = wvl >> 1;                     // LDS pair slot
  const bool lowerw = (khalf == 0);
  const int j  = mtile * 16 + col;                 // hidden index within gate
  const int ab = btile * 16 + col;                 // A-row (batch) this lane loads

  float bias[4];
  const u16* wx[4];
  bf16x8 whr[8][4];                       // Whh fragments, THIS K-half only
#pragma unroll
  for(int g = 0; g < 4; ++g){
    const int row = g * NH + j;           // PyTorch gate order i,f,g,o
    bias[g] = bih[row] + bhh[row];
    wx[g] = Wih + (size_t)row * NE + khalf * 128 + quad * 8;
    const u16* whp = Whh + (size_t)row * NH + khalf * 256 + quad * 8;
#pragma unroll
    for(int i = 0; i < 8; ++i)
      whr[i][g] = *(const bf16x8*)(whp + 32 * i);
  }
  const int* idp = ids + ab * NL;         // ids is [B, L]
  float creg[4] = {0.f, 0.f, 0.f, 0.f};   // cell state (lower wave only live)

  u64 hb[16];                             // h K-half fragment
  f32x4 acc[4];

  // x-part of t=0 (this wave's K-half of NE)
  {
    const u16* xr = emb + (size_t)idp[0] * NE + khalf * 128 + quad * 8;
#pragma unroll
    for(int g = 0; g < 4; ++g) acc[g] = (f32x4){0.f, 0.f, 0.f, 0.f};
#pragma unroll
    for(int k0 = 0; k0 < 128; k0 += 32){
      const bf16x8 af = *(const bf16x8*)(xr + k0);
#pragma unroll
      for(int g = 0; g < 4; ++g)
        acc[g] = __builtin_amdgcn_mfma_f32_16x16x32_bf16(af, *(const bf16x8*)(wx[g] + k0), acc[g], 0, 0, 0);
    }
  }

  for(int t = 0; t < NL; ++t){
    // h-part for step t (hb = K-half of h_{t-1}, polled last iteration)
    if(t > 0){
#pragma unroll
      for(int i = 0; i < 8; ++i){
        const bf16x8 af = mk8(hb[2 * i], hb[2 * i + 1]);
#pragma unroll
        for(int g = 0; g < 4; ++g)
          acc[g] = __builtin_amdgcn_mfma_f32_16x16x32_bf16(af, whr[i][g], acc[g], 0, 0, 0);
      }
    }
    // issue next-step emb loads NOW: latency hides under barrier+epilogue
    bf16x8 xa0, xa1, xa2, xa3;
    const u16* xr = (t + 1 < NL) ? (emb + (size_t)idp[t + 1] * NE + khalf * 128 + quad * 8) : emb;
    xa0 = *(const bf16x8*)(xr);
    xa1 = *(const bf16x8*)(xr + 32);
    xa2 = *(const bf16x8*)(xr + 64);
    xa3 = *(const bf16x8*)(xr + 96);

    // K-half merge: upper writes partial acc; one barrier; lower sums + epilogue
    if(!lowerw){
#pragma unroll
      for(int g = 0; g < 4; ++g)
        pacc[(((t & 1) * 2 + pairid) * 4 + g) * 64 + lane] = acc[g];
    }
    __syncthreads();
    if(lowerw){
#pragma unroll
      for(int g = 0; g < 4; ++g){
        const f32x4 pa = pacc[(((t & 1) * 2 + pairid) * 4 + g) * 64 + lane];
        acc[g][0] += pa[0]; acc[g][1] += pa[1]; acc[g][2] += pa[2]; acc[g][3] += pa[3];
      }
      const u64 pst = ((t >> 4) & 1) ? STM : 0ull;
      u16* ho = hroll + (size_t)(t & (RS - 1)) * NBNH;
#pragma unroll
      for(int r = 0; r < 4; ++r){
        const float gi = acc[0][r] + bias[0];
        const float gf = acc[1][r] + bias[1];
        const float gg = acc[2][r] + bias[2];
        const float go = acc[3][r] + bias[3];
        creg[r] = sigm(gf) * creg[r] + sigm(gi) * tanh_(gg);
        const u32 raw  = (u32)f2bf(sigm(go) * tanh_(creg[r]));
        const u32 pair = raw | (((u32)__shfl_xor((int)raw, 1, 64)) << 16);
        const u32 hi   = (u32)__shfl_xor((int)pair, 2, 64);
        if((col & 3) == 0){
          const int row = btile * 16 + quad * 4 + r;
          st64((u64*)(ho + (size_t)row * NH + mtile * 16 + col),
               ((u64)pair | ((u64)hi << 32)) | pst);
        }
      }
    }
    if(t + 1 < NL){
      // x-part of t+1 from the pre-issued registers
#pragma unroll
      for(int g = 0; g < 4; ++g) acc[g] = (f32x4){0.f, 0.f, 0.f, 0.f};
#pragma unroll
      for(int g = 0; g < 4; ++g){
        acc[g] = __builtin_amdgcn_mfma_f32_16x16x32_bf16(xa0, *(const bf16x8*)(wx[g]),      acc[g], 0, 0, 0);
        acc[g] = __builtin_amdgcn_mfma_f32_16x16x32_bf16(xa1, *(const bf16x8*)(wx[g] + 32), acc[g], 0, 0, 0);
        acc[g] = __builtin_amdgcn_mfma_f32_16x16x32_bf16(xa2, *(const bf16x8*)(wx[g] + 64), acc[g], 0, 0, 0);
        acc[g] = __builtin_amdgcn_mfma_f32_16x16x32_bf16(xa3, *(const bf16x8*)(wx[g] + 96), acc[g], 0, 0, 0);
      }
      // poll h_t K-half straight from the ring (no LDS hop, no sleep)
      {
        const u16* ha = hroll + (size_t)(t & (RS - 1)) * NBNH + (size_t)ab * NH + khalf * 256 + quad * 8;
        const u64 want = ((t >> 4) & 1) ? STM : 0ull;
        for(;;){
          bool ok = true;
#pragma unroll
          for(int i = 0; i < 8; ++i){
            const u64* p = (const u64*)(ha + 32 * i);
            hb[2 * i]     = ald64(p);
            hb[2 * i + 1] = ald64(p + 1);
            ok = ok && ((hb[2 * i] & STM) == want) && ((hb[2 * i + 1] & STM) == want);
          }
          if(__ballot(ok) == ~0ull) break;
        }
#pragma unroll
        for(int i = 0; i < 16; ++i) hb[i] &= CLRM;
      }
    }
  }
}

// ---------------------------------------------------------------------------
// Decoder, K-SPLIT + XCD-PINNED RING: 256 blocks, 90 KB dyn LDS -> 1/CU.
// XCD 0..3: ranks 0..15 producers (local-L2 ring in hroll, same scheme as
// enc; dec phases continue cleanly from enc's final all-STM slot state);
// ranks 16..31 mirrors: poll the local ring and re-publish h_t to hdX with
// agent stores (write-once, 0x4000-stamped) so the cross-XCD store-ack cost
// is OFF the recurrence chain. XCD 4..7: 128 attention workers (R1 path,
// stride 128). c0 = enc h_511 = ring slot 15.
// ---------------------------------------------------------------------------
__global__ void __launch_bounds__(256, 1) dec_kernel(
    const u16* __restrict__ Whh, const float* __restrict__ bih, const float* __restrict__ bhh,
    const float* __restrict__ W2, const float* __restrict__ b2,
    const float* __restrict__ vt, const float* __restrict__ vtb,
    const u16* __restrict__ bl,  u16* hroll,
    const float* __restrict__ h0f,
    u16* hdX, float* __restrict__ out, u32* cnt)
{
  extern __shared__ char dynsm[];
  f32x4* pacc = (f32x4*)dynsm;            // [2][2][4][64]
  __shared__ u32 srank;
  __shared__ __align__(16) float h_f[NH];
  __shared__ __align__(16) float u_lds[NW];
  __shared__ __align__(16) float vt_lds[NW];
  __shared__ float red[8];

  const int tid  = threadIdx.x;
  const int lane = tid & 63;
  const int wvl  = tid >> 6;
  const int col  = lane & 15;
  const int quad = lane >> 4;

  const u32 xcd = xcc_id();
  if(xcd < 4){
    if(tid == 0) srank = atomicAdd(&cnt[8 + xcd], 1u);
    __syncthreads();
    const u32 rank = srank;
    const int btile = (int)xcd;

    if(rank >= 16){
      // ---------------- mirror: ring -> hdX (agent), cols [(rank-16)*32, +32) ----------------
      if(rank >= 32 || tid >= 128) return;
      const int jm = (int)rank - 16;
      const int row = btile * 16 + (tid & 15);
      const int chunk = jm * 8 + ((tid >> 4) & 7);     // u64 index within row
      for(int t = 0; t < NT; ++t){
        const u64* rp = (const u64*)(hroll + (size_t)(t & (RS - 1)) * NBNH) + (size_t)row * (NH / 4) + chunk;
        const u64 want = ((t >> 4) & 1) ? STM : 0ull;
        u64 v;
        for(;;){
          v = ald64(rp);
          if((v & STM) == want) break;
          __builtin_amdgcn_s_sleep(1);
        }
        ast64((u64*)(hdX + (size_t)t * NBNH) + (size_t)row * (NH / 4) + chunk,
              (v & CLRM) | STM);
      }
      return;
    }

    // ------------------------------ producer ------------------------------
    const int mtile  = (int)rank * 2 + (wvl >> 1);
    const int khalf  = wvl & 1;
    const int pairid = wvl >> 1;
    const bool lowerw = (khalf == 0);
    const int j  = mtile * 16 + col;
    const int ab = btile * 16 + col;

    float bias[4];
    bf16x8 whr[8][4];
#pragma unroll
    for(int g = 0; g < 4; ++g){
      const int row = g * NH + j;
      bias[g] = bih[row] + bhh[row];
      const u16* whp = Whh + (size_t)row * NH + khalf * 256 + quad * 8;
#pragma unroll
      for(int i = 0; i < 8; ++i)
        whr[i][g] = *(const bf16x8*)(whp + 32 * i);
    }
    float creg[4] = {0.f, 0.f, 0.f, 0.f};
    if(lowerw){
      // c0 = enc h_511 (ring slot 15; stamp bits set -> mask)
#pragma unroll
      for(int r = 0; r < 4; ++r){
        const int ci = (btile * 16 + quad * 4 + r) * NH + j;
        creg[r] = bf2f((u16)(hroll[(size_t)15 * NBNH + ci] & 0xBFFFu));
      }
    }
    u64 hb[16];
    f32x4 acc[4];

    // t=0 h-part: h_{-1} = h0 (fp32), this wave's K-half
    {
      const float* hp = h0f + (size_t)ab * NH + khalf * 256 + quad * 8;
#pragma unroll
      for(int g = 0; g < 4; ++g) acc[g] = (f32x4){0.f, 0.f, 0.f, 0.f};
#pragma unroll
      for(int i = 0; i < 8; ++i){
        const f32x4 a0 = *(const f32x4*)(hp + 32 * i);
        const f32x4 a1 = *(const f32x4*)(hp + 32 * i + 4);
        bf16x8 af;
#pragma unroll
        for(int q = 0; q < 4; ++q){ af[q] = (short)f2bf(a0[q]); af[q + 4] = (short)f2bf(a1[q]); }
#pragma unroll
        for(int g = 0; g < 4; ++g)
          acc[g] = __builtin_amdgcn_mfma_f32_16x16x32_bf16(af, whr[i][g], acc[g], 0, 0, 0);
      }
    }

    for(int t = 0; t < NT; ++t){
      if(t > 0){
#pragma unroll
        for(int g = 0; g < 4; ++g) acc[g] = (f32x4){0.f, 0.f, 0.f, 0.f};
#pragma unroll
        for(int i = 0; i < 8; ++i){
          const bf16x8 af = mk8(hb[2 * i], hb[2 * i + 1]);
#pragma unroll
          for(int g = 0; g < 4; ++g)
            acc[g] = __builtin_amdgcn_mfma_f32_16x16x32_bf16(af, whr[i][g], acc[g], 0, 0, 0);
        }
      }
      if(!lowerw){
#pragma unroll
        for(int g = 0; g < 4; ++g)
          pacc[(((t & 1) * 2 + pairid) * 4 + g) * 64 + lane] = acc[g];
      }
      __syncthreads();
      if(lowerw){
#pragma unroll
        for(int g = 0; g < 4; ++g){
          const f32x4 pa = pacc[(((t & 1) * 2 + pairid) * 4 + g) * 64 + lane];
          acc[g][0] += pa[0]; acc[g][1] += pa[1]; acc[g][2] += pa[2]; acc[g][3] += pa[3];
        }
        const u64 pst = ((t >> 4) & 1) ? STM : 0ull;
        u16* ho = hroll + (size_t)(t & (RS - 1)) * NBNH;
#pragma unroll
        for(int r = 0; r < 4; ++r){
          const float gi = acc[0][r] + bias[0];
          const float gf = acc[1][r] + bias[1];
          const float gg = acc[2][r] + bias[2];
          const float go = acc[3][r] + bias[3];
          creg[r] = sigm(gf) * creg[r] + sigm(gi) * tanh_(gg);
          const u32 raw  = (u32)f2bf(sigm(go) * tanh_(creg[r]));
          const u32 pair = raw | (((u32)__shfl_xor((int)raw, 1, 64)) << 16);
          const u32 hi   = (u32)__shfl_xor((int)pair, 2, 64);
          if((col & 3) == 0){
            const int row = btile * 16 + quad * 4 + r;
            st64((u64*)(ho + (size_t)row * NH + mtile * 16 + col),
                 ((u64)pair | ((u64)hi << 32)) | pst);
          }
        }
      }
      if(t + 1 < NT){
        const u16* ha = hroll + (size_t)(t & (RS - 1)) * NBNH + (size_t)ab * NH + khalf * 256 + quad * 8;
        const u64 want = ((t >> 4) & 1) ? STM : 0ull;
        for(;;){
          bool ok = true;
#pragma unroll
          for(int i = 0; i < 8; ++i){
            const u64* p = (const u64*)(ha + 32 * i);
            hb[2 * i]     = ald64(p);
            hb[2 * i + 1] = ald64(p + 1);
            ok = ok && ((hb[2 * i] & STM) == want) && ((hb[2 * i + 1] & STM) == want);
          }
          if(__ballot(ok) == ~0ull) break;
        }
#pragma unroll
        for(int i = 0; i < 16; ++i) hb[i] &= CLRM;
      }
    }
    return;
  }

  // ------------------------- attention worker path (XCD 4..7) -------------------------
  if(tid == 0) srank = atomicAdd(&cnt[12], 1u);
  __syncthreads();
  const int wid = (int)srank;             // 0..127

  vt_lds[tid] = vt[tid];
  const float vtbf = vtb[0];
  __syncthreads();

  f32x4 bacc[4];
#pragma unroll
  for(int g = 0; g < 4; ++g) bacc[g] = (f32x4){0.f, 0.f, 0.f, 0.f};
  const bf16x8 junk = {0, 0, 0, 0, 0, 0, 0, 0};

  for(int tk = wid; tk < NT * NB; tk += 128){
    const int t = tk >> 6;
    const int b = tk & 63;

    // poll slot t row b (stamped bf16 from the mirrors), stage -> fp32 LDS
    {
      const u32* hp = (const u32*)(hdX + (size_t)t * NBNH + (size_t)b * NH);
      u32 v;
      for(;;){
        v = ald32(hp + tid);
        burn32(bacc, junk);
        const int ok = ((v & 0x40004000u) == 0x40004000u) ? 1 : 0;
        if(__syncthreads_and(ok)) break;
      }
      h_f[2 * tid]     = bf2f((u16)(v & 0xBFFFu));
      h_f[2 * tid + 1] = bf2f((u16)((v >> 16) & 0xBFFFu));
    }
    __syncthreads();

    // u[n] = b2[n] + h . W2[n,:]   (h broadcast from LDS, f32x4 loads)
    {
      const float* w2r = W2 + (size_t)tid * NH;
      float s = b2[tid];
#pragma unroll 4
      for(int k = 0; k < NH; k += 4){
        const f32x4 hv = *(const f32x4*)(&h_f[k]);
        const f32x4 wv = *(const f32x4*)(w2r + k);
        s += hv[0] * wv[0] + hv[1] * wv[1] + hv[2] * wv[2] + hv[3] * wv[3];
      }
      u_lds[tid] = s;
    }
    __syncthreads();

    // scores for l = tid and l = tid+256 (bf16x8 row loads)
    float a0, a1;
#pragma unroll
    for(int e = 0; e < 2; ++e){
      const int l = tid + e * 256;
      const u16* br = bl + (size_t)(l * NB + b) * NW;
      float p = 0.f;
#pragma unroll 2
      for(int w0 = 0; w0 < NW; w0 += 8){
        const bf16x8 bv = *(const bf16x8*)(br + w0);
#pragma unroll
        for(int q = 0; q < 8; ++q)
          p += vt_lds[w0 + q] * tanh_(bf2f((u16)bv[q]) + u_lds[w0 + q]);
      }
      if(e == 0) a0 = p + vtbf; else a1 = p + vtbf;
    }

    // log-softmax over L = 512 (2 values per thread, block-wide reduction)
    float mx = fmaxf(a0, a1);
#pragma unroll
    for(int off = 32; off > 0; off >>= 1) mx = fmaxf(mx, __shfl_xor(mx, off, 64));
    if(lane == 0) red[wvl] = mx;
    __syncthreads();
    mx = fmaxf(fmaxf(red[0], red[1]), fmaxf(red[2], red[3]));
    float es = __expf(a0 - mx) + __expf(a1 - mx);
#pragma unroll
    for(int off = 32; off > 0; off >>= 1) es += __shfl_xor(es, off, 64);
    if(lane == 0) red[4 + wvl] = es;
    __syncthreads();
    const float lse = mx + logf(red[4] + red[5] + red[6] + red[7]);
    out[((size_t)tid * NB + b) * NT + t]         = a0 - lse;
    out[((size_t)(tid + 256) * NB + b) * NT + t] = a1 - lse;
    __syncthreads();
  }
  burn_sink(bacc);
}

// ---------------------------------------------------------------------------
extern "C" void kernel_launch(void* const* d_in, const int* in_sizes, int n_in,
                              void* d_out, int out_size, void* d_ws, size_t ws_size,
                              hipStream_t stream)
{
  (void)in_sizes; (void)n_in; (void)out_size; (void)ws_size;
  const int*   ids  = (const int*)d_in[0];
  const float* emb  = (const float*)d_in[1];
  const float* eWih = (const float*)d_in[2];
  const float* eWhh = (const float*)d_in[3];
  const float* ebih = (const float*)d_in[4];
  const float* ebhh = (const float*)d_in[5];
  /* d_in[6] = dec_Wih: unused (decoder input is identically zero) */
  const float* dWhh = (const float*)d_in[7];
  const float* dbih = (const float*)d_in[8];
  const float* dbhh = (const float*)d_in[9];
  const float* W1   = (const float*)d_in[10];
  const float* b1   = (const float*)d_in[11];
  const float* W2   = (const float*)d_in[12];
  const float* b2   = (const float*)d_in[13];
  const float* vt   = (const float*)d_in[14];
  const float* vtb  = (const float*)d_in[15];
  const float* h0   = (const float*)d_in[16];

  // workspace ~28.5 MB. X = bf16 emb during enc, then dec's 64 write-once h
  // slots (hdX, stamped by the mirrors). hroll = 16-deep local-L2 h ring,
  // shared by enc (t mod 16) and dec (phases continue; c0 = slot 15).
  char* ws = (char*)d_ws;
  u16* bl     = (u16*)ws; ws += (size_t)NL * NB * NW * 2;    // blend1 bf16  16.78 MB
  u16* hroll  = (u16*)ws; ws += (size_t)RS * NBNH * 2;       // h ring       1.05 MB
  u16* X      = (u16*)ws; ws += (size_t)10000 * NE * 2;      // emb_b / hdec 5.12 MB
  u16* eWih_b = (u16*)ws; ws += (size_t)4 * NH * NE * 2;     // 1.05 MB
  u16* eWhh_b = (u16*)ws; ws += (size_t)4 * NH * NH * 2;     // 2.10 MB
  u16* dWhh_b = (u16*)ws; ws += (size_t)4 * NH * NH * 2;     // 2.10 MB
  u16* W1_b   = (u16*)ws; ws += (size_t)NW * NH * 2;         // 0.26 MB
  u32* cnt    = (u32*)ws; ws += 1024;                        // rank/worker counters

  // ring slots pre-filled with stamp-1 pattern (phase-0 writes flip to 0);
  // counters zeroed (enc: cnt[0..3], dec: cnt[8..12])
  hipLaunchKernelGGL(fill_kernel, dim3((RS * NBNH / 2) / 256), dim3(256), 0, stream,
                     (u32*)hroll, 0x40004000u);
  hipLaunchKernelGGL(fill_kernel, dim3(1), dim3(256), 0, stream, cnt, 0u);
  hipLaunchKernelGGL(cvt_kernel, dim3(10000), dim3(256), 0, stream, emb,  X,      10000 * NE);
  hipLaunchKernelGGL(cvt_kernel, dim3(2048),  dim3(256), 0, stream, eWih, eWih_b, 4 * NH * NE);
  hipLaunchKernelGGL(cvt_kernel, dim3(4096),  dim3(256), 0, stream, eWhh, eWhh_b, 4 * NH * NH);
  hipLaunchKernelGGL(cvt_kernel, dim3(4096),  dim3(256), 0, stream, dWhh, dWhh_b, 4 * NH * NH);
  hipLaunchKernelGGL(cvt_kernel, dim3(512),   dim3(256), 0, stream, W1,   W1_b,   NW * NH);

  // 90 KB dynamic LDS -> 1 block/CU -> 256-block grid is a bijection onto
  // CUs -> every XCD hosts exactly 32 blocks (placement pigeonhole)
  hipLaunchKernelGGL(enc_kernel, dim3(256), dim3(256), 92160, stream,
                     ids, X, eWih_b, eWhh_b, ebih, ebhh, W1_b, b1, hroll, bl, cnt);
  hipLaunchKernelGGL(dec_kernel, dim3(256), dim3(256), 92160, stream,
                     dWhh_b, dbih, dbhh, W2, b2, vt, vtb, bl, hroll, h0, X,
                     (float*)d_out, cnt);
}

// Round 3
// 4043.468 us; speedup vs baseline: 1.4628x; 1.0875x over previous
//
#include <hip/hip_runtime.h>

#define NB 64      // batch
#define NL 512     // seq len
#define NT 64      // answer len
#define NH 512     // hidden
#define NE 256     // emb dim
#define NW 256     // attention weight dim
#define NBNH (NB * NH)
#define RS 16      // h-ring depth (slots); phase stamp = (t>>4)&1

typedef __attribute__((ext_vector_type(8))) short bf16x8;
typedef __attribute__((ext_vector_type(4))) float f32x4;
typedef unsigned short u16;
typedef unsigned int u32;
typedef unsigned long long u64;

#define STM 0x4000400040004000ull   // bit14 of each u16 (never set in bf16 of |v|<2)
#define CLRM 0xBFFFBFFFBFFFBFFFull

__device__ __forceinline__ float bf2f(u16 v){
  union { u32 u; float f; } x; x.u = ((u32)v) << 16; return x.f;
}
__device__ __forceinline__ u16 f2bf(float f){
  union { float f; u32 u; } x; x.f = f;
  return (u16)((x.u + 0x7FFFu + ((x.u >> 16) & 1u)) >> 16);
}
__device__ __forceinline__ float sigm(float x){ return 1.f / (1.f + __expf(-x)); }
__device__ __forceinline__ float tanh_(float x){ float e = __expf(2.f * x); return 1.f - 2.f / (e + 1.f); }

// agent-scope load: bypasses L1; hits the local-XCD L2 for locally-written lines
__device__ __forceinline__ u64 ald64(const u64* p){
  return __hip_atomic_load(p, __ATOMIC_RELAXED, __HIP_MEMORY_SCOPE_AGENT);
}
__device__ __forceinline__ u32 ald32(const u32* p){
  return __hip_atomic_load(p, __ATOMIC_RELAXED, __HIP_MEMORY_SCOPE_AGENT);
}
// agent-scope store: pushes to the device coherence point (cross-XCD safe)
__device__ __forceinline__ void ast64(u64* p, u64 v){
  __hip_atomic_store(p, v, __ATOMIC_RELAXED, __HIP_MEMORY_SCOPE_AGENT);
}
// workgroup-scope store: plain store, write-through L1 -> LOCAL L2 only
__device__ __forceinline__ void st64(u64* p, u64 v){
  __hip_atomic_store(p, v, __ATOMIC_RELAXED, __HIP_MEMORY_SCOPE_WORKGROUP);
}
__device__ __forceinline__ void st32(u32* p, u32 v){
  __hip_atomic_store(p, v, __ATOMIC_RELAXED, __HIP_MEMORY_SCOPE_WORKGROUP);
}
__device__ __forceinline__ bf16x8 mk8(u64 a, u64 b){
  union { u64 q[2]; bf16x8 v; } u; u.q[0] = a; u.q[1] = b; return u.v;
}
__device__ __forceinline__ u32 xcc_id(){
  u32 x;
  asm volatile("s_getreg_b32 %0, hwreg(HW_REG_XCC_ID)" : "=s"(x));
  return x & 7u;
}
// MFMA burn while polling (dec attention workers only)
__device__ __forceinline__ void burn32(f32x4* bacc, bf16x8 junk){
#pragma unroll
  for(int i = 0; i < 8; ++i)
#pragma unroll
    for(int g = 0; g < 4; ++g)
      bacc[g] = __builtin_amdgcn_mfma_f32_16x16x32_bf16(junk, junk, bacc[g], 0, 0, 0);
}
__device__ __forceinline__ void burn_sink(f32x4* bacc){
  asm volatile("" :: "v"(bacc[0][0]), "v"(bacc[1][0]), "v"(bacc[2][0]), "v"(bacc[3][0]));
}

__global__ void fill_kernel(u32* p, u32 v){
  p[blockIdx.x * 256 + threadIdx.x] = v;
}

// fp32 -> bf16 (round-to-nearest-even)
__global__ void cvt_kernel(const float* __restrict__ src, u16* __restrict__ dst, int n){
  const int i = blockIdx.x * 256 + threadIdx.x;
  if(i < n) dst[i] = f2bf(src[i]);
}

// ---------------------------------------------------------------------------
// Encoder, K-SPLIT + FLAG DOORBELL: 256 blocks x 90 KB dyn LDS -> 1 block/CU.
// XCD 0..3: ranks 0..15 producers, 16..31 blend1 workers. XCD 4..7 exit.
// R2 evidence: per-step 5.7 us vs ~0.5 us structural floor with everything
// idle => the no-sleep data polls (4-8 KB/wave/iter x 80 waves/XCD) saturate
// the local L2 request queues. Fix: producers publish a 4-byte per-mtile flag
// after their stamped data stores; consumers spin on the flag lines only
// (64-128 B/wave/iter, ~60x less poll traffic) and then run the stamped data
// load as a verify-once loop (correctness backstop unchanged from R2).
// ---------------------------------------------------------------------------
__global__ void __launch_bounds__(256, 1) enc_kernel(
    const int* __restrict__ ids, const u16* __restrict__ emb,
    const u16* __restrict__ Wih, const u16* __restrict__ Whh,
    const float* __restrict__ bih, const float* __restrict__ bhh,
    const u16* __restrict__ W1,  const float* __restrict__ b1,
    u16* hroll, u16* bl, u32* cnt, u32* flags)
{
  extern __shared__ char dynsm[];         // 90 KB reserved (1 block/CU forcing)
  f32x4* pacc = (f32x4*)dynsm;            // [2 buf][2 pair][4 gate][64 lane]
  __shared__ u32 srank;

  const int lane = threadIdx.x & 63;
  const int wvl  = threadIdx.x >> 6;      // 0..3
  const int col  = lane & 15;
  const int quad = lane >> 4;

  const u32 xcd = xcc_id();
  if(xcd >= 4) return;
  if(threadIdx.x == 0) srank = atomicAdd(&cnt[xcd], 1u);
  __syncthreads();
  const u32 rank = srank;
  const int btile = (int)xcd;
  u32* fbase = flags + (size_t)xcd * (RS * 32);   // [slot][mtile]

  if(rank >= 16){
    // ---------------- blend1 worker: cols [ (rank-16)*16, +16 ) ----------------
    if(rank >= 32 || wvl != 0) return;    // 1 wave per worker block
    const int n1 = ((int)rank - 16) * 16 + col;
    bf16x8 w1f[16];                       // W1 row n1, register-cached
    const u16* w1p = W1 + (size_t)n1 * NH + quad * 8;
#pragma unroll
    for(int i = 0; i < 16; ++i) w1f[i] = *(const bf16x8*)(w1p + 32 * i);
    const float b1f = b1[n1];
    const int arow = btile * 16 + col;    // h row this lane holds as A-frag

    for(int t = 0; t < NL; ++t){
      const int slot = t & (RS - 1);
      const u32 fwant = (u32)((t >> 4) & 1);
      // flag poll: all 32 mtiles of this slot (128 B / wave / iter)
      {
        const u32* fp = fbase + slot * 32;
        for(;;){
          const u32 f = ald32(fp + (lane & 31));
          if(__ballot(f == fwant) == ~0ull) break;
          __builtin_amdgcn_s_sleep(1);
        }
      }
      const u16* ha = hroll + (size_t)slot * NBNH + (size_t)arow * NH + quad * 8;
      const u64 want = fwant ? STM : 0ull;
      u64 hw[32];
      for(;;){                            // verify-once (flag raced data: rare)
        bool ok = true;
#pragma unroll
        for(int i = 0; i < 16; ++i){
          const u64* p = (const u64*)(ha + 32 * i);
          hw[2 * i]     = ald64(p);
          hw[2 * i + 1] = ald64(p + 1);
          ok = ok && ((hw[2 * i] & STM) == want) && ((hw[2 * i + 1] & STM) == want);
        }
        if(__ballot(ok) == ~0ull) break;
      }
      f32x4 a2 = {0.f, 0.f, 0.f, 0.f};
#pragma unroll
      for(int i = 0; i < 16; ++i)
        a2 = __builtin_amdgcn_mfma_f32_16x16x32_bf16(
               mk8(hw[2 * i] & CLRM, hw[2 * i + 1] & CLRM), w1f[i], a2, 0, 0, 0);
#pragma unroll
      for(int r = 0; r < 4; ++r){
        const int b = btile * 16 + quad * 4 + r;
        bl[((size_t)t * NB + b) * NW + n1] = f2bf(a2[r] + b1f);
      }
    }
    return;
  }

  // ------------------------------ producer ------------------------------
  const int mtile  = (int)rank * 2 + (wvl >> 1);   // 0..31
  const int khalf  = wvl & 1;                      // K-half of the recurrence
  const int pairid = wvl >> 1;                     // LDS pair slot
  const bool lowerw = (khalf == 0);
  const int j  = mtile * 16 + col;                 // hidden index within gate
  const int ab = btile * 16 + col;                 // A-row (batch) this lane loads

  float bias[4];
  const u16* wx[4];
  bf16x8 whr[8][4];                       // Whh fragments, THIS K-half only
#pragma unroll
  for(int g = 0; g < 4; ++g){
    const int row = g * NH + j;           // PyTorch gate order i,f,g,o
    bias[g] = bih[row] + bhh[row];
    wx[g] = Wih + (size_t)row * NE + khalf * 128 + quad * 8;
    const u16* whp = Whh + (size_t)row * NH + khalf * 256 + quad * 8;
#pragma unroll
    for(int i = 0; i < 8; ++i)
      whr[i][g] = *(const bf16x8*)(whp + 32 * i);
  }
  const int* idp = ids + ab * NL;         // ids is [B, L]
  float creg[4] = {0.f, 0.f, 0.f, 0.f};   // cell state (lower wave only live)

  u64 hb[16];                             // h K-half fragment
  f32x4 acc[4];

  // x-part of t=0 (this wave's K-half of NE)
  {
    const u16* xr = emb + (size_t)idp[0] * NE + khalf * 128 + quad * 8;
#pragma unroll
    for(int g = 0; g < 4; ++g) acc[g] = (f32x4){0.f, 0.f, 0.f, 0.f};
#pragma unroll
    for(int k0 = 0; k0 < 128; k0 += 32){
      const bf16x8 af = *(const bf16x8*)(xr + k0);
#pragma unroll
      for(int g = 0; g < 4; ++g)
        acc[g] = __builtin_amdgcn_mfma_f32_16x16x32_bf16(af, *(const bf16x8*)(wx[g] + k0), acc[g], 0, 0, 0);
    }
  }

  for(int t = 0; t < NL; ++t){
    // h-part for step t (hb = K-half of h_{t-1}, polled last iteration)
    if(t > 0){
#pragma unroll
      for(int i = 0; i < 8; ++i){
        const bf16x8 af = mk8(hb[2 * i], hb[2 * i + 1]);
#pragma unroll
        for(int g = 0; g < 4; ++g)
          acc[g] = __builtin_amdgcn_mfma_f32_16x16x32_bf16(af, whr[i][g], acc[g], 0, 0, 0);
      }
    }
    // issue next-step emb loads NOW: latency hides under barrier+epilogue
    bf16x8 xa0, xa1, xa2, xa3;
    const u16* xr = (t + 1 < NL) ? (emb + (size_t)idp[t + 1] * NE + khalf * 128 + quad * 8) : emb;
    xa0 = *(const bf16x8*)(xr);
    xa1 = *(const bf16x8*)(xr + 32);
    xa2 = *(const bf16x8*)(xr + 64);
    xa3 = *(const bf16x8*)(xr + 96);

    const int slot = t & (RS - 1);
    const u32 fphase = (u32)((t >> 4) & 1);

    // K-half merge: upper writes partial acc; one barrier; lower sums + epilogue
    if(!lowerw){
#pragma unroll
      for(int g = 0; g < 4; ++g)
        pacc[(((t & 1) * 2 + pairid) * 4 + g) * 64 + lane] = acc[g];
    }
    __syncthreads();
    if(lowerw){
#pragma unroll
      for(int g = 0; g < 4; ++g){
        const f32x4 pa = pacc[(((t & 1) * 2 + pairid) * 4 + g) * 64 + lane];
        acc[g][0] += pa[0]; acc[g][1] += pa[1]; acc[g][2] += pa[2]; acc[g][3] += pa[3];
      }
      const u64 pst = fphase ? STM : 0ull;
      u16* ho = hroll + (size_t)slot * NBNH;
#pragma unroll
      for(int r = 0; r < 4; ++r){
        const float gi = acc[0][r] + bias[0];
        const float gf = acc[1][r] + bias[1];
        const float gg = acc[2][r] + bias[2];
        const float go = acc[3][r] + bias[3];
        creg[r] = sigm(gf) * creg[r] + sigm(gi) * tanh_(gg);
        const u32 raw  = (u32)f2bf(sigm(go) * tanh_(creg[r]));
        const u32 pair = raw | (((u32)__shfl_xor((int)raw, 1, 64)) << 16);
        const u32 hi   = (u32)__shfl_xor((int)pair, 2, 64);
        if((col & 3) == 0){
          const int row = btile * 16 + quad * 4 + r;
          st64((u64*)(ho + (size_t)row * NH + mtile * 16 + col),
               ((u64)pair | ((u64)hi << 32)) | pst);
        }
      }
      // flag doorbell (advisory; data stamps remain the correctness gate)
      if(lane == 0) st32(fbase + slot * 32 + mtile, fphase);
    }
    if(t + 1 < NL){
      // x-part of t+1 from the pre-issued registers
#pragma unroll
      for(int g = 0; g < 4; ++g) acc[g] = (f32x4){0.f, 0.f, 0.f, 0.f};
#pragma unroll
      for(int g = 0; g < 4; ++g){
        acc[g] = __builtin_amdgcn_mfma_f32_16x16x32_bf16(xa0, *(const bf16x8*)(wx[g]),      acc[g], 0, 0, 0);
        acc[g] = __builtin_amdgcn_mfma_f32_16x16x32_bf16(xa1, *(const bf16x8*)(wx[g] + 32), acc[g], 0, 0, 0);
        acc[g] = __builtin_amdgcn_mfma_f32_16x16x32_bf16(xa2, *(const bf16x8*)(wx[g] + 64), acc[g], 0, 0, 0);
        acc[g] = __builtin_amdgcn_mfma_f32_16x16x32_bf16(xa3, *(const bf16x8*)(wx[g] + 96), acc[g], 0, 0, 0);
      }
      // flag poll: this K-half's 16 mtile flags (64 B / wave / iter)
      {
        const u32* fp = fbase + slot * 32 + khalf * 16;
        for(;;){
          const u32 f = ald32(fp + (lane & 15));
          if(__ballot(f == fphase) == ~0ull) break;
        }
      }
      // data load + stamp verify (usually exactly one pass)
      {
        const u16* ha = hroll + (size_t)slot * NBNH + (size_t)ab * NH + khalf * 256 + quad * 8;
        const u64 want = fphase ? STM : 0ull;
        for(;;){
          bool ok = true;
#pragma unroll
          for(int i = 0; i < 8; ++i){
            const u64* p = (const u64*)(ha + 32 * i);
            hb[2 * i]     = ald64(p);
            hb[2 * i + 1] = ald64(p + 1);
            ok = ok && ((hb[2 * i] & STM) == want) && ((hb[2 * i + 1] & STM) == want);
          }
          if(__ballot(ok) == ~0ull) break;
        }
#pragma unroll
        for(int i = 0; i < 16; ++i) hb[i] &= CLRM;
      }
    }
  }
}

// ---------------------------------------------------------------------------
// Decoder, K-SPLIT + XCD-PINNED RING + FLAG DOORBELL: 256 blocks, 1/CU.
// XCD 0..3: ranks 0..15 producers (ring phases continue from enc; flags
// likewise: enc leaves all flags = 1, dec writes phase 0 first wrap);
// ranks 16..31 mirrors (ring -> hdX agent republish). XCD 4..7: 128
// attention workers. c0 = enc h_511 = ring slot 15.
// ---------------------------------------------------------------------------
__global__ void __launch_bounds__(256, 1) dec_kernel(
    const u16* __restrict__ Whh, const float* __restrict__ bih, const float* __restrict__ bhh,
    const float* __restrict__ W2, const float* __restrict__ b2,
    const float* __restrict__ vt, const float* __restrict__ vtb,
    const u16* __restrict__ bl,  u16* hroll,
    const float* __restrict__ h0f,
    u16* hdX, float* __restrict__ out, u32* cnt, u32* flags)
{
  extern __shared__ char dynsm[];
  f32x4* pacc = (f32x4*)dynsm;            // [2][2][4][64]
  __shared__ u32 srank;
  __shared__ __align__(16) float h_f[NH];
  __shared__ __align__(16) float u_lds[NW];
  __shared__ __align__(16) float vt_lds[NW];
  __shared__ float red[8];

  const int tid  = threadIdx.x;
  const int lane = tid & 63;
  const int wvl  = tid >> 6;
  const int col  = lane & 15;
  const int quad = lane >> 4;

  const u32 xcd = xcc_id();
  if(xcd < 4){
    if(tid == 0) srank = atomicAdd(&cnt[8 + xcd], 1u);
    __syncthreads();
    const u32 rank = srank;
    const int btile = (int)xcd;
    u32* fbase = flags + (size_t)xcd * (RS * 32);

    if(rank >= 16){
      // ---------------- mirror: ring -> hdX (agent), cols [(rank-16)*32, +32) ----------------
      if(rank >= 32 || tid >= 128) return;
      const int jm = (int)rank - 16;
      const int row = btile * 16 + (tid & 15);
      const int chunk = jm * 8 + ((tid >> 4) & 7);     // u64 index within row
      const int fmt = chunk >> 2;                      // mtile owning this chunk
      for(int t = 0; t < NT; ++t){
        const int slot = t & (RS - 1);
        const u32 fwant = (u32)((t >> 4) & 1);
        for(;;){
          if(ald32(fbase + slot * 32 + fmt) == fwant) break;
          __builtin_amdgcn_s_sleep(1);
        }
        const u64* rp = (const u64*)(hroll + (size_t)slot * NBNH) + (size_t)row * (NH / 4) + chunk;
        const u64 want = fwant ? STM : 0ull;
        u64 v;
        for(;;){
          v = ald64(rp);
          if((v & STM) == want) break;
        }
        ast64((u64*)(hdX + (size_t)t * NBNH) + (size_t)row * (NH / 4) + chunk,
              (v & CLRM) | STM);
      }
      return;
    }

    // ------------------------------ producer ------------------------------
    const int mtile  = (int)rank * 2 + (wvl >> 1);
    const int khalf  = wvl & 1;
    const int pairid = wvl >> 1;
    const bool lowerw = (khalf == 0);
    const int j  = mtile * 16 + col;
    const int ab = btile * 16 + col;

    float bias[4];
    bf16x8 whr[8][4];
#pragma unroll
    for(int g = 0; g < 4; ++g){
      const int row = g * NH + j;
      bias[g] = bih[row] + bhh[row];
      const u16* whp = Whh + (size_t)row * NH + khalf * 256 + quad * 8;
#pragma unroll
      for(int i = 0; i < 8; ++i)
        whr[i][g] = *(const bf16x8*)(whp + 32 * i);
    }
    float creg[4] = {0.f, 0.f, 0.f, 0.f};
    if(lowerw){
      // c0 = enc h_511 (ring slot 15; stamp bits set -> mask)
#pragma unroll
      for(int r = 0; r < 4; ++r){
        const int ci = (btile * 16 + quad * 4 + r) * NH + j;
        creg[r] = bf2f((u16)(hroll[(size_t)15 * NBNH + ci] & 0xBFFFu));
      }
    }
    u64 hb[16];
    f32x4 acc[4];

    // t=0 h-part: h_{-1} = h0 (fp32), this wave's K-half
    {
      const float* hp = h0f + (size_t)ab * NH + khalf * 256 + quad * 8;
#pragma unroll
      for(int g = 0; g < 4; ++g) acc[g] = (f32x4){0.f, 0.f, 0.f, 0.f};
#pragma unroll
      for(int i = 0; i < 8; ++i){
        const f32x4 a0 = *(const f32x4*)(hp + 32 * i);
        const f32x4 a1 = *(const f32x4*)(hp + 32 * i + 4);
        bf16x8 af;
#pragma unroll
        for(int q = 0; q < 4; ++q){ af[q] = (short)f2bf(a0[q]); af[q + 4] = (short)f2bf(a1[q]); }
#pragma unroll
        for(int g = 0; g < 4; ++g)
          acc[g] = __builtin_amdgcn_mfma_f32_16x16x32_bf16(af, whr[i][g], acc[g], 0, 0, 0);
      }
    }

    for(int t = 0; t < NT; ++t){
      if(t > 0){
#pragma unroll
        for(int g = 0; g < 4; ++g) acc[g] = (f32x4){0.f, 0.f, 0.f, 0.f};
#pragma unroll
        for(int i = 0; i < 8; ++i){
          const bf16x8 af = mk8(hb[2 * i], hb[2 * i + 1]);
#pragma unroll
          for(int g = 0; g < 4; ++g)
            acc[g] = __builtin_amdgcn_mfma_f32_16x16x32_bf16(af, whr[i][g], acc[g], 0, 0, 0);
        }
      }
      const int slot = t & (RS - 1);
      const u32 fphase = (u32)((t >> 4) & 1);
      if(!lowerw){
#pragma unroll
        for(int g = 0; g < 4; ++g)
          pacc[(((t & 1) * 2 + pairid) * 4 + g) * 64 + lane] = acc[g];
      }
      __syncthreads();
      if(lowerw){
#pragma unroll
        for(int g = 0; g < 4; ++g){
          const f32x4 pa = pacc[(((t & 1) * 2 + pairid) * 4 + g) * 64 + lane];
          acc[g][0] += pa[0]; acc[g][1] += pa[1]; acc[g][2] += pa[2]; acc[g][3] += pa[3];
        }
        const u64 pst = fphase ? STM : 0ull;
        u16* ho = hroll + (size_t)slot * NBNH;
#pragma unroll
        for(int r = 0; r < 4; ++r){
          const float gi = acc[0][r] + bias[0];
          const float gf = acc[1][r] + bias[1];
          const float gg = acc[2][r] + bias[2];
          const float go = acc[3][r] + bias[3];
          creg[r] = sigm(gf) * creg[r] + sigm(gi) * tanh_(gg);
          const u32 raw  = (u32)f2bf(sigm(go) * tanh_(creg[r]));
          const u32 pair = raw | (((u32)__shfl_xor((int)raw, 1, 64)) << 16);
          const u32 hi   = (u32)__shfl_xor((int)pair, 2, 64);
          if((col & 3) == 0){
            const int row = btile * 16 + quad * 4 + r;
            st64((u64*)(ho + (size_t)row * NH + mtile * 16 + col),
                 ((u64)pair | ((u64)hi << 32)) | pst);
          }
        }
        if(lane == 0) st32(fbase + slot * 32 + mtile, fphase);
      }
      if(t + 1 < NT){
        // flag poll, then stamped data verify
        {
          const u32* fp = fbase + slot * 32 + khalf * 16;
          for(;;){
            const u32 f = ald32(fp + (lane & 15));
            if(__ballot(f == fphase) == ~0ull) break;
          }
        }
        const u16* ha = hroll + (size_t)slot * NBNH + (size_t)ab * NH + khalf * 256 + quad * 8;
        const u64 want = fphase ? STM : 0ull;
        for(;;){
          bool ok = true;
#pragma unroll
          for(int i = 0; i < 8; ++i){
            const u64* p = (const u64*)(ha + 32 * i);
            hb[2 * i]     = ald64(p);
            hb[2 * i + 1] = ald64(p + 1);
            ok = ok && ((hb[2 * i] & STM) == want) && ((hb[2 * i + 1] & STM) == want);
          }
          if(__ballot(ok) == ~0ull) break;
        }
#pragma unroll
        for(int i = 0; i < 16; ++i) hb[i] &= CLRM;
      }
    }
    return;
  }

  // ------------------------- attention worker path (XCD 4..7) -------------------------
  if(tid == 0) srank = atomicAdd(&cnt[12], 1u);
  __syncthreads();
  const int wid = (int)srank;             // 0..127

  vt_lds[tid] = vt[tid];
  const float vtbf = vtb[0];
  __syncthreads();

  f32x4 bacc[4];
#pragma unroll
  for(int g = 0; g < 4; ++g) bacc[g] = (f32x4){0.f, 0.f, 0.f, 0.f};
  const bf16x8 junk = {0, 0, 0, 0, 0, 0, 0, 0};

  for(int tk = wid; tk < NT * NB; tk += 128){
    const int t = tk >> 6;
    const int b = tk & 63;

    // poll slot t row b (stamped bf16 from the mirrors), stage -> fp32 LDS
    {
      const u32* hp = (const u32*)(hdX + (size_t)t * NBNH + (size_t)b * NH);
      u32 v;
      for(;;){
        v = ald32(hp + tid);
        burn32(bacc, junk);
        const int ok = ((v & 0x40004000u) == 0x40004000u) ? 1 : 0;
        if(__syncthreads_and(ok)) break;
      }
      h_f[2 * tid]     = bf2f((u16)(v & 0xBFFFu));
      h_f[2 * tid + 1] = bf2f((u16)((v >> 16) & 0xBFFFu));
    }
    __syncthreads();

    // u[n] = b2[n] + h . W2[n,:]   (h broadcast from LDS, f32x4 loads)
    {
      const float* w2r = W2 + (size_t)tid * NH;
      float s = b2[tid];
#pragma unroll 4
      for(int k = 0; k < NH; k += 4){
        const f32x4 hv = *(const f32x4*)(&h_f[k]);
        const f32x4 wv = *(const f32x4*)(w2r + k);
        s += hv[0] * wv[0] + hv[1] * wv[1] + hv[2] * wv[2] + hv[3] * wv[3];
      }
      u_lds[tid] = s;
    }
    __syncthreads();

    // scores for l = tid and l = tid+256 (bf16x8 row loads)
    float a0, a1;
#pragma unroll
    for(int e = 0; e < 2; ++e){
      const int l = tid + e * 256;
      const u16* br = bl + (size_t)(l * NB + b) * NW;
      float p = 0.f;
#pragma unroll 2
      for(int w0 = 0; w0 < NW; w0 += 8){
        const bf16x8 bv = *(const bf16x8*)(br + w0);
#pragma unroll
        for(int q = 0; q < 8; ++q)
          p += vt_lds[w0 + q] * tanh_(bf2f((u16)bv[q]) + u_lds[w0 + q]);
      }
      if(e == 0) a0 = p + vtbf; else a1 = p + vtbf;
    }

    // log-softmax over L = 512 (2 values per thread, block-wide reduction)
    float mx = fmaxf(a0, a1);
#pragma unroll
    for(int off = 32; off > 0; off >>= 1) mx = fmaxf(mx, __shfl_xor(mx, off, 64));
    if(lane == 0) red[wvl] = mx;
    __syncthreads();
    mx = fmaxf(fmaxf(red[0], red[1]), fmaxf(red[2], red[3]));
    float es = __expf(a0 - mx) + __expf(a1 - mx);
#pragma unroll
    for(int off = 32; off > 0; off >>= 1) es += __shfl_xor(es, off, 64);
    if(lane == 0) red[4 + wvl] = es;
    __syncthreads();
    const float lse = mx + logf(red[4] + red[5] + red[6] + red[7]);
    out[((size_t)tid * NB + b) * NT + t]         = a0 - lse;
    out[((size_t)(tid + 256) * NB + b) * NT + t] = a1 - lse;
    __syncthreads();
  }
  burn_sink(bacc);
}

// ---------------------------------------------------------------------------
extern "C" void kernel_launch(void* const* d_in, const int* in_sizes, int n_in,
                              void* d_out, int out_size, void* d_ws, size_t ws_size,
                              hipStream_t stream)
{
  (void)in_sizes; (void)n_in; (void)out_size; (void)ws_size;
  const int*   ids  = (const int*)d_in[0];
  const float* emb  = (const float*)d_in[1];
  const float* eWih = (const float*)d_in[2];
  const float* eWhh = (const float*)d_in[3];
  const float* ebih = (const float*)d_in[4];
  const float* ebhh = (const float*)d_in[5];
  /* d_in[6] = dec_Wih: unused (decoder input is identically zero) */
  const float* dWhh = (const float*)d_in[7];
  const float* dbih = (const float*)d_in[8];
  const float* dbhh = (const float*)d_in[9];
  const float* W1   = (const float*)d_in[10];
  const float* b1   = (const float*)d_in[11];
  const float* W2   = (const float*)d_in[12];
  const float* b2   = (const float*)d_in[13];
  const float* vt   = (const float*)d_in[14];
  const float* vtb  = (const float*)d_in[15];
  const float* h0   = (const float*)d_in[16];

  // workspace ~28.5 MB. X = bf16 emb during enc, then dec's 64 write-once h
  // slots (hdX). hroll = 16-deep local-L2 h ring (enc t mod 16; dec continues
  // phases, c0 = slot 15). flags = per-XCD per-slot per-mtile doorbells
  // (enc leaves all = 1; dec's first wrap writes 0 -> phases continue).
  char* ws = (char*)d_ws;
  u16* bl     = (u16*)ws; ws += (size_t)NL * NB * NW * 2;    // blend1 bf16  16.78 MB
  u16* hroll  = (u16*)ws; ws += (size_t)RS * NBNH * 2;       // h ring       1.05 MB
  u16* X      = (u16*)ws; ws += (size_t)10000 * NE * 2;      // emb_b / hdec 5.12 MB
  u16* eWih_b = (u16*)ws; ws += (size_t)4 * NH * NE * 2;     // 1.05 MB
  u16* eWhh_b = (u16*)ws; ws += (size_t)4 * NH * NH * 2;     // 2.10 MB
  u16* dWhh_b = (u16*)ws; ws += (size_t)4 * NH * NH * 2;     // 2.10 MB
  u16* W1_b   = (u16*)ws; ws += (size_t)NW * NH * 2;         // 0.26 MB
  u32* cnt    = (u32*)ws; ws += 1024;                        // rank/worker counters
  u32* flags  = (u32*)ws; ws += (size_t)4 * RS * 32 * 4;     // doorbells 8 KB

  // ring + flags pre-filled with phase-1 pattern; counters zeroed
  hipLaunchKernelGGL(fill_kernel, dim3((RS * NBNH / 2) / 256), dim3(256), 0, stream,
                     (u32*)hroll, 0x40004000u);
  hipLaunchKernelGGL(fill_kernel, dim3(8), dim3(256), 0, stream, flags, 1u);
  hipLaunchKernelGGL(fill_kernel, dim3(1), dim3(256), 0, stream, cnt, 0u);
  hipLaunchKernelGGL(cvt_kernel, dim3(10000), dim3(256), 0, stream, emb,  X,      10000 * NE);
  hipLaunchKernelGGL(cvt_kernel, dim3(2048),  dim3(256), 0, stream, eWih, eWih_b, 4 * NH * NE);
  hipLaunchKernelGGL(cvt_kernel, dim3(4096),  dim3(256), 0, stream, eWhh, eWhh_b, 4 * NH * NH);
  hipLaunchKernelGGL(cvt_kernel, dim3(4096),  dim3(256), 0, stream, dWhh, dWhh_b, 4 * NH * NH);
  hipLaunchKernelGGL(cvt_kernel, dim3(512),   dim3(256), 0, stream, W1,   W1_b,   NW * NH);

  // 90 KB dynamic LDS -> 1 block/CU -> 256-block grid is a bijection onto
  // CUs -> every XCD hosts exactly 32 blocks (placement pigeonhole)
  hipLaunchKernelGGL(enc_kernel, dim3(256), dim3(256), 92160, stream,
                     ids, X, eWih_b, eWhh_b, ebih, ebhh, W1_b, b1, hroll, bl, cnt, flags);
  hipLaunchKernelGGL(dec_kernel, dim3(256), dim3(256), 92160, stream,
                     dWhh_b, dbih, dbhh, W2, b2, vt, vtb, bl, hroll, h0, X,
                     (float*)d_out, cnt, flags);
}

// Round 7
// 3986.882 us; speedup vs baseline: 1.4836x; 1.0142x over previous
//
#include <hip/hip_runtime.h>

#define NB 64      // batch
#define NL 512     // seq len
#define NT 64      // answer len
#define NH 512     // hidden
#define NE 256     // emb dim
#define NW 256     // attention weight dim
#define NBNH (NB * NH)
#define RS 16      // h-ring depth (slots); phase stamp = (t>>4)&1

typedef __attribute__((ext_vector_type(8))) short bf16x8;
typedef __attribute__((ext_vector_type(4))) float f32x4;
typedef unsigned short u16;
typedef unsigned int u32;
typedef unsigned long long u64;

#define STM 0x4000400040004000ull   // bit14 of each u16 (never set in bf16 of |v|<2)
#define CLRM 0xBFFFBFFFBFFFBFFFull

__device__ __forceinline__ float bf2f(u16 v){
  union { u32 u; float f; } x; x.u = ((u32)v) << 16; return x.f;
}
__device__ __forceinline__ u16 f2bf(float f){
  union { float f; u32 u; } x; x.f = f;
  return (u16)((x.u + 0x7FFFu + ((x.u >> 16) & 1u)) >> 16);
}
__device__ __forceinline__ float sigm(float x){ return 1.f / (1.f + __expf(-x)); }
__device__ __forceinline__ float tanh_(float x){ float e = __expf(2.f * x); return 1.f - 2.f / (e + 1.f); }

// agent-scope load: bypasses L1; hits the local-XCD L2 for locally-written lines
__device__ __forceinline__ u64 ald64(const u64* p){
  return __hip_atomic_load(p, __ATOMIC_RELAXED, __HIP_MEMORY_SCOPE_AGENT);
}
__device__ __forceinline__ u32 ald32(const u32* p){
  return __hip_atomic_load(p, __ATOMIC_RELAXED, __HIP_MEMORY_SCOPE_AGENT);
}
// agent-scope store: pushes to the device coherence point (cross-XCD safe)
__device__ __forceinline__ void ast64(u64* p, u64 v){
  __hip_atomic_store(p, v, __ATOMIC_RELAXED, __HIP_MEMORY_SCOPE_AGENT);
}
__device__ __forceinline__ void ast32(u32* p, u32 v){
  __hip_atomic_store(p, v, __ATOMIC_RELAXED, __HIP_MEMORY_SCOPE_AGENT);
}
// workgroup-scope store: plain store, write-through L1 -> LOCAL L2 only
__device__ __forceinline__ void st64(u64* p, u64 v){
  __hip_atomic_store(p, v, __ATOMIC_RELAXED, __HIP_MEMORY_SCOPE_WORKGROUP);
}
__device__ __forceinline__ void st32(u32* p, u32 v){
  __hip_atomic_store(p, v, __ATOMIC_RELAXED, __HIP_MEMORY_SCOPE_WORKGROUP);
}
__device__ __forceinline__ bf16x8 mk8(u64 a, u64 b){
  union { u64 q[2]; bf16x8 v; } u; u.q[0] = a; u.q[1] = b; return u.v;
}
__device__ __forceinline__ u32 xcc_id(){
  u32 x;
  asm volatile("s_getreg_b32 %0, hwreg(HW_REG_XCC_ID)" : "=s"(x));
  return x & 7u;
}
// MFMA burn: holds DVFS clocks up on otherwise-idle CUs. R0 counters
// normalize to ~870 MHz effective clock when the chip is 96% idle; R1
// proved sustained burn keeps MfmaUtil 66% over a 4.7 ms dispatch.
__device__ __forceinline__ void burn32(f32x4* bacc, bf16x8 junk){
#pragma unroll
  for(int i = 0; i < 8; ++i)
#pragma unroll
    for(int g = 0; g < 4; ++g)
      bacc[g] = __builtin_amdgcn_mfma_f32_16x16x32_bf16(junk, junk, bacc[g], 0, 0, 0);
}
__device__ __forceinline__ void burn_sink(f32x4* bacc){
  asm volatile("" :: "v"(bacc[0][0]), "v"(bacc[1][0]), "v"(bacc[2][0]), "v"(bacc[3][0]));
}

__global__ void fill_kernel(u32* p, u32 v){
  p[blockIdx.x * 256 + threadIdx.x] = v;
}

// fp32 -> bf16 (round-to-nearest-even)
__global__ void cvt_kernel(const float* __restrict__ src, u16* __restrict__ dst, int n){
  const int i = blockIdx.x * 256 + threadIdx.x;
  if(i < n) dst[i] = f2bf(src[i]);
}

// ---------------------------------------------------------------------------
// Encoder, K-SPLIT + FLAG DOORBELL + BURN-ON-IDLE: 256 blocks x 90 KB dyn
// LDS -> 1 block/CU. XCD 0..3: ranks 0..15 producers (R3 core, untouched),
// 16..31 blend1 workers (burn instead of sleep). XCD 4..7: 128 burner blocks
// hold the clock up until a per-XCD done flag (agent-scope) is set by the
// rank-0 producer. R3 evidence: lean structure (~3.5K cy/step) ran at ~700
// MHz because the chip was 96% idle -> 5.06 us/step.
// ---------------------------------------------------------------------------
__global__ void __launch_bounds__(256, 1) enc_kernel(
    const int* __restrict__ ids, const u16* __restrict__ emb,
    const u16* __restrict__ Wih, const u16* __restrict__ Whh,
    const float* __restrict__ bih, const float* __restrict__ bhh,
    const u16* __restrict__ W1,  const float* __restrict__ b1,
    u16* hroll, u16* bl, u32* cnt, u32* flags)
{
  extern __shared__ char dynsm[];         // 90 KB reserved (1 block/CU forcing)
  f32x4* pacc = (f32x4*)dynsm;            // [2 buf][2 pair][4 gate][64 lane]
  __shared__ u32 srank;

  const int lane = threadIdx.x & 63;
  const int wvl  = threadIdx.x >> 6;      // 0..3
  const int col  = lane & 15;
  const int quad = lane >> 4;

  const u32 xcd = xcc_id();
  if(xcd >= 4){
    // ---------------- burner: keep the clock domain hot ----------------
    f32x4 bacc[4];
#pragma unroll
    for(int g = 0; g < 4; ++g) bacc[g] = (f32x4){0.f, 0.f, 0.f, 0.f};
    const bf16x8 junk = {0, 0, 0, 0, 0, 0, 0, 0};
    const u32* dp = cnt + 64 + (xcd & 3);
    for(;;){
      if(ald32(dp) != 0u) break;
      burn32(bacc, junk); burn32(bacc, junk);
      burn32(bacc, junk); burn32(bacc, junk);
    }
    burn_sink(bacc);
    return;
  }
  if(threadIdx.x == 0) srank = atomicAdd(&cnt[xcd], 1u);
  __syncthreads();
  const u32 rank = srank;
  const int btile = (int)xcd;
  u32* fbase = flags + (size_t)xcd * (RS * 32);   // [slot][mtile]

  if(rank >= 16){
    if(rank >= 32) return;
    f32x4 bacc[4];
#pragma unroll
    for(int g = 0; g < 4; ++g) bacc[g] = (f32x4){0.f, 0.f, 0.f, 0.f};
    const bf16x8 junk = {0, 0, 0, 0, 0, 0, 0, 0};
    if(wvl != 0){
      // extra worker waves: burn until this XCD's producers finish
      const u32* dp = cnt + 64 + xcd;
      for(;;){
        if(ald32(dp) != 0u) break;
        burn32(bacc, junk); burn32(bacc, junk);
        burn32(bacc, junk); burn32(bacc, junk);
      }
      burn_sink(bacc);
      return;
    }
    // ---------------- blend1 worker: cols [ (rank-16)*16, +16 ) ----------------
    const int n1 = ((int)rank - 16) * 16 + col;
    bf16x8 w1f[16];                       // W1 row n1, register-cached
    const u16* w1p = W1 + (size_t)n1 * NH + quad * 8;
#pragma unroll
    for(int i = 0; i < 16; ++i) w1f[i] = *(const bf16x8*)(w1p + 32 * i);
    const float b1f = b1[n1];
    const int arow = btile * 16 + col;    // h row this lane holds as A-frag

    for(int t = 0; t < NL; ++t){
      const int slot = t & (RS - 1);
      const u32 fwant = (u32)((t >> 4) & 1);
      // flag poll: all 32 mtiles of this slot; burn between misses
      {
        const u32* fp = fbase + slot * 32;
        for(;;){
          const u32 f = ald32(fp + (lane & 31));
          if(__ballot(f == fwant) == ~0ull) break;
          burn32(bacc, junk);
        }
      }
      const u16* ha = hroll + (size_t)slot * NBNH + (size_t)arow * NH + quad * 8;
      const u64 want = fwant ? STM : 0ull;
      u64 hw[32];
      for(;;){                            // verify-once (flag raced data: rare)
        bool ok = true;
#pragma unroll
        for(int i = 0; i < 16; ++i){
          const u64* p = (const u64*)(ha + 32 * i);
          hw[2 * i]     = ald64(p);
          hw[2 * i + 1] = ald64(p + 1);
          ok = ok && ((hw[2 * i] & STM) == want) && ((hw[2 * i + 1] & STM) == want);
        }
        if(__ballot(ok) == ~0ull) break;
      }
      f32x4 a2 = {0.f, 0.f, 0.f, 0.f};
#pragma unroll
      for(int i = 0; i < 16; ++i)
        a2 = __builtin_amdgcn_mfma_f32_16x16x32_bf16(
               mk8(hw[2 * i] & CLRM, hw[2 * i + 1] & CLRM), w1f[i], a2, 0, 0, 0);
#pragma unroll
      for(int r = 0; r < 4; ++r){
        const int b = btile * 16 + quad * 4 + r;
        bl[((size_t)t * NB + b) * NW + n1] = f2bf(a2[r] + b1f);
      }
    }
    burn_sink(bacc);
    return;
  }

  // ------------------------------ producer ------------------------------
  const int mtile  = (int)rank * 2 + (wvl >> 1);   // 0..31
  const int khalf  = wvl & 1;                      // K-half of the recurrence
  const int pairid = wvl >> 1;                     // LDS pair slot
  const bool lowerw = (khalf == 0);
  const int j  = mtile * 16 + col;                 // hidden index within gate
  const int ab = btile * 16 + col;                 // A-row (batch) this lane loads

  float bias[4];
  const u16* wx[4];
  bf16x8 whr[8][4];                       // Whh fragments, THIS K-half only
#pragma unroll
  for(int g = 0; g < 4; ++g){
    const int row = g * NH + j;           // PyTorch gate order i,f,g,o
    bias[g] = bih[row] + bhh[row];
    wx[g] = Wih + (size_t)row * NE + khalf * 128 + quad * 8;
    const u16* whp = Whh + (size_t)row * NH + khalf * 256 + quad * 8;
#pragma unroll
    for(int i = 0; i < 8; ++i)
      whr[i][g] = *(const bf16x8*)(whp + 32 * i);
  }
  const int* idp = ids + ab * NL;         // ids is [B, L]
  float creg[4] = {0.f, 0.f, 0.f, 0.f};   // cell state (lower wave only live)

  u64 hb[16];                             // h K-half fragment
  f32x4 acc[4];

  // x-part of t=0 (this wave's K-half of NE)
  {
    const u16* xr = emb + (size_t)idp[0] * NE + khalf * 128 + quad * 8;
#pragma unroll
    for(int g = 0; g < 4; ++g) acc[g] = (f32x4){0.f, 0.f, 0.f, 0.f};
#pragma unroll
    for(int k0 = 0; k0 < 128; k0 += 32){
      const bf16x8 af = *(const bf16x8*)(xr + k0);
#pragma unroll
      for(int g = 0; g < 4; ++g)
        acc[g] = __builtin_amdgcn_mfma_f32_16x16x32_bf16(af, *(const bf16x8*)(wx[g] + k0), acc[g], 0, 0, 0);
    }
  }

  for(int t = 0; t < NL; ++t){
    // h-part for step t (hb = K-half of h_{t-1}, polled last iteration)
    if(t > 0){
#pragma unroll
      for(int i = 0; i < 8; ++i){
        const bf16x8 af = mk8(hb[2 * i], hb[2 * i + 1]);
#pragma unroll
        for(int g = 0; g < 4; ++g)
          acc[g] = __builtin_amdgcn_mfma_f32_16x16x32_bf16(af, whr[i][g], acc[g], 0, 0, 0);
      }
    }
    // issue next-step emb loads NOW: latency hides under barrier+epilogue
    bf16x8 xa0, xa1, xa2, xa3;
    const u16* xr = (t + 1 < NL) ? (emb + (size_t)idp[t + 1] * NE + khalf * 128 + quad * 8) : emb;
    xa0 = *(const bf16x8*)(xr);
    xa1 = *(const bf16x8*)(xr + 32);
    xa2 = *(const bf16x8*)(xr + 64);
    xa3 = *(const bf16x8*)(xr + 96);

    const int slot = t & (RS - 1);
    const u32 fphase = (u32)((t >> 4) & 1);

    // K-half merge: upper writes partial acc; one barrier; lower sums + epilogue
    if(!lowerw){
#pragma unroll
      for(int g = 0; g < 4; ++g)
        pacc[(((t & 1) * 2 + pairid) * 4 + g) * 64 + lane] = acc[g];
    }
    __syncthreads();
    if(lowerw){
#pragma unroll
      for(int g = 0; g < 4; ++g){
        const f32x4 pa = pacc[(((t & 1) * 2 + pairid) * 4 + g) * 64 + lane];
        acc[g][0] += pa[0]; acc[g][1] += pa[1]; acc[g][2] += pa[2]; acc[g][3] += pa[3];
      }
      const u64 pst = fphase ? STM : 0ull;
      u16* ho = hroll + (size_t)slot * NBNH;
#pragma unroll
      for(int r = 0; r < 4; ++r){
        const float gi = acc[0][r] + bias[0];
        const float gf = acc[1][r] + bias[1];
        const float gg = acc[2][r] + bias[2];
        const float go = acc[3][r] + bias[3];
        creg[r] = sigm(gf) * creg[r] + sigm(gi) * tanh_(gg);
        const u32 raw  = (u32)f2bf(sigm(go) * tanh_(creg[r]));
        const u32 pair = raw | (((u32)__shfl_xor((int)raw, 1, 64)) << 16);
        const u32 hi   = (u32)__shfl_xor((int)pair, 2, 64);
        if((col & 3) == 0){
          const int row = btile * 16 + quad * 4 + r;
          st64((u64*)(ho + (size_t)row * NH + mtile * 16 + col),
               ((u64)pair | ((u64)hi << 32)) | pst);
        }
      }
      // flag doorbell (advisory; data stamps remain the correctness gate)
      if(lane == 0) st32(fbase + slot * 32 + mtile, fphase);
    }
    if(t + 1 < NL){
      // x-part of t+1 from the pre-issued registers
#pragma unroll
      for(int g = 0; g < 4; ++g) acc[g] = (f32x4){0.f, 0.f, 0.f, 0.f};
#pragma unroll
      for(int g = 0; g < 4; ++g){
        acc[g] = __builtin_amdgcn_mfma_f32_16x16x32_bf16(xa0, *(const bf16x8*)(wx[g]),      acc[g], 0, 0, 0);
        acc[g] = __builtin_amdgcn_mfma_f32_16x16x32_bf16(xa1, *(const bf16x8*)(wx[g] + 32), acc[g], 0, 0, 0);
        acc[g] = __builtin_amdgcn_mfma_f32_16x16x32_bf16(xa2, *(const bf16x8*)(wx[g] + 64), acc[g], 0, 0, 0);
        acc[g] = __builtin_amdgcn_mfma_f32_16x16x32_bf16(xa3, *(const bf16x8*)(wx[g] + 96), acc[g], 0, 0, 0);
      }
      // flag poll: this K-half's 16 mtile flags (64 B / wave / iter)
      {
        const u32* fp = fbase + slot * 32 + khalf * 16;
        for(;;){
          const u32 f = ald32(fp + (lane & 15));
          if(__ballot(f == fphase) == ~0ull) break;
        }
      }
      // data load + stamp verify (usually exactly one pass)
      {
        const u16* ha = hroll + (size_t)slot * NBNH + (size_t)ab * NH + khalf * 256 + quad * 8;
        const u64 want = fphase ? STM : 0ull;
        for(;;){
          bool ok = true;
#pragma unroll
          for(int i = 0; i < 8; ++i){
            const u64* p = (const u64*)(ha + 32 * i);
            hb[2 * i]     = ald64(p);
            hb[2 * i + 1] = ald64(p + 1);
            ok = ok && ((hb[2 * i] & STM) == want) && ((hb[2 * i + 1] & STM) == want);
          }
          if(__ballot(ok) == ~0ull) break;
        }
#pragma unroll
        for(int i = 0; i < 16; ++i) hb[i] &= CLRM;
      }
    }
  }
  // signal burners: this XCD's recurrence is done (agent scope, cross-XCD)
  if(rank == 0 && threadIdx.x == 0) ast32(cnt + 64 + (u32)xcd, 1u);
}

// ---------------------------------------------------------------------------
// Decoder, K-SPLIT + XCD-PINNED RING + FLAG DOORBELL: 256 blocks, 1/CU.
// XCD 0..3: ranks 0..15 producers (ring phases continue from enc); ranks
// 16..31 mirrors (ring -> hdX agent republish; burn instead of sleep while
// flag-polling). XCD 4..7: 128 attention workers (burn while polling).
// c0 = enc h_511 = ring slot 15.
// ---------------------------------------------------------------------------
__global__ void __launch_bounds__(256, 1) dec_kernel(
    const u16* __restrict__ Whh, const float* __restrict__ bih, const float* __restrict__ bhh,
    const float* __restrict__ W2, const float* __restrict__ b2,
    const float* __restrict__ vt, const float* __restrict__ vtb,
    const u16* __restrict__ bl,  u16* hroll,
    const float* __restrict__ h0f,
    u16* hdX, float* __restrict__ out, u32* cnt, u32* flags)
{
  extern __shared__ char dynsm[];
  f32x4* pacc = (f32x4*)dynsm;            // [2][2][4][64]
  __shared__ u32 srank;
  __shared__ __align__(16) float h_f[NH];
  __shared__ __align__(16) float u_lds[NW];
  __shared__ __align__(16) float vt_lds[NW];
  __shared__ float red[8];

  const int tid  = threadIdx.x;
  const int lane = tid & 63;
  const int wvl  = tid >> 6;
  const int col  = lane & 15;
  const int quad = lane >> 4;

  const u32 xcd = xcc_id();
  if(xcd < 4){
    if(tid == 0) srank = atomicAdd(&cnt[8 + xcd], 1u);
    __syncthreads();
    const u32 rank = srank;
    const int btile = (int)xcd;
    u32* fbase = flags + (size_t)xcd * (RS * 32);

    if(rank >= 16){
      // ---------------- mirror: ring -> hdX (agent), cols [(rank-16)*32, +32) ----------------
      if(rank >= 32 || tid >= 128) return;
      const int jm = (int)rank - 16;
      const int row = btile * 16 + (tid & 15);
      const int chunk = jm * 8 + ((tid >> 4) & 7);     // u64 index within row
      const int fmt = chunk >> 2;                      // mtile owning this chunk
      f32x4 bacc[4];
#pragma unroll
      for(int g = 0; g < 4; ++g) bacc[g] = (f32x4){0.f, 0.f, 0.f, 0.f};
      const bf16x8 junk = {0, 0, 0, 0, 0, 0, 0, 0};
      for(int t = 0; t < NT; ++t){
        const int slot = t & (RS - 1);
        const u32 fwant = (u32)((t >> 4) & 1);
        for(;;){
          if(ald32(fbase + slot * 32 + fmt) == fwant) break;
          burn32(bacc, junk);
        }
        const u64* rp = (const u64*)(hroll + (size_t)slot * NBNH) + (size_t)row * (NH / 4) + chunk;
        const u64 want = fwant ? STM : 0ull;
        u64 v;
        for(;;){
          v = ald64(rp);
          if((v & STM) == want) break;
        }
        ast64((u64*)(hdX + (size_t)t * NBNH) + (size_t)row * (NH / 4) + chunk,
              (v & CLRM) | STM);
      }
      burn_sink(bacc);
      return;
    }

    // ------------------------------ producer ------------------------------
    const int mtile  = (int)rank * 2 + (wvl >> 1);
    const int khalf  = wvl & 1;
    const int pairid = wvl >> 1;
    const bool lowerw = (khalf == 0);
    const int j  = mtile * 16 + col;
    const int ab = btile * 16 + col;

    float bias[4];
    bf16x8 whr[8][4];
#pragma unroll
    for(int g = 0; g < 4; ++g){
      const int row = g * NH + j;
      bias[g] = bih[row] + bhh[row];
      const u16* whp = Whh + (size_t)row * NH + khalf * 256 + quad * 8;
#pragma unroll
      for(int i = 0; i < 8; ++i)
        whr[i][g] = *(const bf16x8*)(whp + 32 * i);
    }
    float creg[4] = {0.f, 0.f, 0.f, 0.f};
    if(lowerw){
      // c0 = enc h_511 (ring slot 15; stamp bits set -> mask)
#pragma unroll
      for(int r = 0; r < 4; ++r){
        const int ci = (btile * 16 + quad * 4 + r) * NH + j;
        creg[r] = bf2f((u16)(hroll[(size_t)15 * NBNH + ci] & 0xBFFFu));
      }
    }
    u64 hb[16];
    f32x4 acc[4];

    // t=0 h-part: h_{-1} = h0 (fp32), this wave's K-half
    {
      const float* hp = h0f + (size_t)ab * NH + khalf * 256 + quad * 8;
#pragma unroll
      for(int g = 0; g < 4; ++g) acc[g] = (f32x4){0.f, 0.f, 0.f, 0.f};
#pragma unroll
      for(int i = 0; i < 8; ++i){
        const f32x4 a0 = *(const f32x4*)(hp + 32 * i);
        const f32x4 a1 = *(const f32x4*)(hp + 32 * i + 4);
        bf16x8 af;
#pragma unroll
        for(int q = 0; q < 4; ++q){ af[q] = (short)f2bf(a0[q]); af[q + 4] = (short)f2bf(a1[q]); }
#pragma unroll
        for(int g = 0; g < 4; ++g)
          acc[g] = __builtin_amdgcn_mfma_f32_16x16x32_bf16(af, whr[i][g], acc[g], 0, 0, 0);
      }
    }

    for(int t = 0; t < NT; ++t){
      if(t > 0){
#pragma unroll
        for(int g = 0; g < 4; ++g) acc[g] = (f32x4){0.f, 0.f, 0.f, 0.f};
#pragma unroll
        for(int i = 0; i < 8; ++i){
          const bf16x8 af = mk8(hb[2 * i], hb[2 * i + 1]);
#pragma unroll
          for(int g = 0; g < 4; ++g)
            acc[g] = __builtin_amdgcn_mfma_f32_16x16x32_bf16(af, whr[i][g], acc[g], 0, 0, 0);
        }
      }
      const int slot = t & (RS - 1);
      const u32 fphase = (u32)((t >> 4) & 1);
      if(!lowerw){
#pragma unroll
        for(int g = 0; g < 4; ++g)
          pacc[(((t & 1) * 2 + pairid) * 4 + g) * 64 + lane] = acc[g];
      }
      __syncthreads();
      if(lowerw){
#pragma unroll
        for(int g = 0; g < 4; ++g){
          const f32x4 pa = pacc[(((t & 1) * 2 + pairid) * 4 + g) * 64 + lane];
          acc[g][0] += pa[0]; acc[g][1] += pa[1]; acc[g][2] += pa[2]; acc[g][3] += pa[3];
        }
        const u64 pst = fphase ? STM : 0ull;
        u16* ho = hroll + (size_t)slot * NBNH;
#pragma unroll
        for(int r = 0; r < 4; ++r){
          const float gi = acc[0][r] + bias[0];
          const float gf = acc[1][r] + bias[1];
          const float gg = acc[2][r] + bias[2];
          const float go = acc[3][r] + bias[3];
          creg[r] = sigm(gf) * creg[r] + sigm(gi) * tanh_(gg);
          const u32 raw  = (u32)f2bf(sigm(go) * tanh_(creg[r]));
          const u32 pair = raw | (((u32)__shfl_xor((int)raw, 1, 64)) << 16);
          const u32 hi   = (u32)__shfl_xor((int)pair, 2, 64);
          if((col & 3) == 0){
            const int row = btile * 16 + quad * 4 + r;
            st64((u64*)(ho + (size_t)row * NH + mtile * 16 + col),
                 ((u64)pair | ((u64)hi << 32)) | pst);
          }
        }
        if(lane == 0) st32(fbase + slot * 32 + mtile, fphase);
      }
      if(t + 1 < NT){
        // flag poll, then stamped data verify
        {
          const u32* fp = fbase + slot * 32 + khalf * 16;
          for(;;){
            const u32 f = ald32(fp + (lane & 15));
            if(__ballot(f == fphase) == ~0ull) break;
          }
        }
        const u16* ha = hroll + (size_t)slot * NBNH + (size_t)ab * NH + khalf * 256 + quad * 8;
        const u64 want = fphase ? STM : 0ull;
        for(;;){
          bool ok = true;
#pragma unroll
          for(int i = 0; i < 8; ++i){
            const u64* p = (const u64*)(ha + 32 * i);
            hb[2 * i]     = ald64(p);
            hb[2 * i + 1] = ald64(p + 1);
            ok = ok && ((hb[2 * i] & STM) == want) && ((hb[2 * i + 1] & STM) == want);
          }
          if(__ballot(ok) == ~0ull) break;
        }
#pragma unroll
        for(int i = 0; i < 16; ++i) hb[i] &= CLRM;
      }
    }
    return;
  }

  // ------------------------- attention worker path (XCD 4..7) -------------------------
  if(tid == 0) srank = atomicAdd(&cnt[12], 1u);
  __syncthreads();
  const int wid = (int)srank;             // 0..127

  vt_lds[tid] = vt[tid];
  const float vtbf = vtb[0];
  __syncthreads();

  f32x4 bacc[4];
#pragma unroll
  for(int g = 0; g < 4; ++g) bacc[g] = (f32x4){0.f, 0.f, 0.f, 0.f};
  const bf16x8 junk = {0, 0, 0, 0, 0, 0, 0, 0};

  for(int tk = wid; tk < NT * NB; tk += 128){
    const int t = tk >> 6;
    const int b = tk & 63;

    // poll slot t row b (stamped bf16 from the mirrors), stage -> fp32 LDS
    {
      const u32* hp = (const u32*)(hdX + (size_t)t * NBNH + (size_t)b * NH);
      u32 v;
      for(;;){
        v = ald32(hp + tid);
        burn32(bacc, junk);
        const int ok = ((v & 0x40004000u) == 0x40004000u) ? 1 : 0;
        if(__syncthreads_and(ok)) break;
      }
      h_f[2 * tid]     = bf2f((u16)(v & 0xBFFFu));
      h_f[2 * tid + 1] = bf2f((u16)((v >> 16) & 0xBFFFu));
    }
    __syncthreads();

    // u[n] = b2[n] + h . W2[n,:]   (h broadcast from LDS, f32x4 loads)
    {
      const float* w2r = W2 + (size_t)tid * NH;
      float s = b2[tid];
#pragma unroll 4
      for(int k = 0; k < NH; k += 4){
        const f32x4 hv = *(const f32x4*)(&h_f[k]);
        const f32x4 wv = *(const f32x4*)(w2r + k);
        s += hv[0] * wv[0] + hv[1] * wv[1] + hv[2] * wv[2] + hv[3] * wv[3];
      }
      u_lds[tid] = s;
    }
    __syncthreads();

    // scores for l = tid and l = tid+256 (bf16x8 row loads)
    float a0, a1;
#pragma unroll
    for(int e = 0; e < 2; ++e){
      const int l = tid + e * 256;
      const u16* br = bl + (size_t)(l * NB + b) * NW;
      float p = 0.f;
#pragma unroll 2
      for(int w0 = 0; w0 < NW; w0 += 8){
        const bf16x8 bv = *(const bf16x8*)(br + w0);
#pragma unroll
        for(int q = 0; q < 8; ++q)
          p += vt_lds[w0 + q] * tanh_(bf2f((u16)bv[q]) + u_lds[w0 + q]);
      }
      if(e == 0) a0 = p + vtbf; else a1 = p + vtbf;
    }

    // log-softmax over L = 512 (2 values per thread, block-wide reduction)
    float mx = fmaxf(a0, a1);
#pragma unroll
    for(int off = 32; off > 0; off >>= 1) mx = fmaxf(mx, __shfl_xor(mx, off, 64));
    if(lane == 0) red[wvl] = mx;
    __syncthreads();
    mx = fmaxf(fmaxf(red[0], red[1]), fmaxf(red[2], red[3]));
    float es = __expf(a0 - mx) + __expf(a1 - mx);
#pragma unroll
    for(int off = 32; off > 0; off >>= 1) es += __shfl_xor(es, off, 64);
    if(lane == 0) red[4 + wvl] = es;
    __syncthreads();
    const float lse = mx + logf(red[4] + red[5] + red[6] + red[7]);
    out[((size_t)tid * NB + b) * NT + t]         = a0 - lse;
    out[((size_t)(tid + 256) * NB + b) * NT + t] = a1 - lse;
    __syncthreads();
  }
  burn_sink(bacc);
}

// ---------------------------------------------------------------------------
extern "C" void kernel_launch(void* const* d_in, const int* in_sizes, int n_in,
                              void* d_out, int out_size, void* d_ws, size_t ws_size,
                              hipStream_t stream)
{
  (void)in_sizes; (void)n_in; (void)out_size; (void)ws_size;
  const int*   ids  = (const int*)d_in[0];
  const float* emb  = (const float*)d_in[1];
  const float* eWih = (const float*)d_in[2];
  const float* eWhh = (const float*)d_in[3];
  const float* ebih = (const float*)d_in[4];
  const float* ebhh = (const float*)d_in[5];
  /* d_in[6] = dec_Wih: unused (decoder input is identically zero) */
  const float* dWhh = (const float*)d_in[7];
  const float* dbih = (const float*)d_in[8];
  const float* dbhh = (const float*)d_in[9];
  const float* W1   = (const float*)d_in[10];
  const float* b1   = (const float*)d_in[11];
  const float* W2   = (const float*)d_in[12];
  const float* b2   = (const float*)d_in[13];
  const float* vt   = (const float*)d_in[14];
  const float* vtb  = (const float*)d_in[15];
  const float* h0   = (const float*)d_in[16];

  // workspace ~28.5 MB. X = bf16 emb during enc, then dec's 64 write-once h
  // slots (hdX). hroll = 16-deep local-L2 h ring (enc t mod 16; dec continues
  // phases, c0 = slot 15). flags = per-XCD per-slot per-mtile doorbells
  // (enc leaves all = 1; dec's first wrap writes 0 -> phases continue).
  // cnt[64..67] = per-XCD encoder-done flags (burner exit).
  char* ws = (char*)d_ws;
  u16* bl     = (u16*)ws; ws += (size_t)NL * NB * NW * 2;    // blend1 bf16  16.78 MB
  u16* hroll  = (u16*)ws; ws += (size_t)RS * NBNH * 2;       // h ring       1.05 MB
  u16* X      = (u16*)ws; ws += (size_t)10000 * NE * 2;      // emb_b / hdec 5.12 MB
  u16* eWih_b = (u16*)ws; ws += (size_t)4 * NH * NE * 2;     // 1.05 MB
  u16* eWhh_b = (u16*)ws; ws += (size_t)4 * NH * NH * 2;     // 2.10 MB
  u16* dWhh_b = (u16*)ws; ws += (size_t)4 * NH * NH * 2;     // 2.10 MB
  u16* W1_b   = (u16*)ws; ws += (size_t)NW * NH * 2;         // 0.26 MB
  u32* cnt    = (u32*)ws; ws += 1024;                        // rank/done counters
  u32* flags  = (u32*)ws; ws += (size_t)4 * RS * 32 * 4;     // doorbells 8 KB

  // ring + flags pre-filled with phase-1 pattern; counters zeroed
  hipLaunchKernelGGL(fill_kernel, dim3((RS * NBNH / 2) / 256), dim3(256), 0, stream,
                     (u32*)hroll, 0x40004000u);
  hipLaunchKernelGGL(fill_kernel, dim3(8), dim3(256), 0, stream, flags, 1u);
  hipLaunchKernelGGL(fill_kernel, dim3(1), dim3(256), 0, stream, cnt, 0u);
  hipLaunchKernelGGL(cvt_kernel, dim3(10000), dim3(256), 0, stream, emb,  X,      10000 * NE);
  hipLaunchKernelGGL(cvt_kernel, dim3(2048),  dim3(256), 0, stream, eWih, eWih_b, 4 * NH * NE);
  hipLaunchKernelGGL(cvt_kernel, dim3(4096),  dim3(256), 0, stream, eWhh, eWhh_b, 4 * NH * NH);
  hipLaunchKernelGGL(cvt_kernel, dim3(4096),  dim3(256), 0, stream, dWhh, dWhh_b, 4 * NH * NH);
  hipLaunchKernelGGL(cvt_kernel, dim3(512),   dim3(256), 0, stream, W1,   W1_b,   NW * NH);

  // 90 KB dynamic LDS -> 1 block/CU -> 256-block grid is a bijection onto
  // CUs -> every XCD hosts exactly 32 blocks (placement pigeonhole)
  hipLaunchKernelGGL(enc_kernel, dim3(256), dim3(256), 92160, stream,
                     ids, X, eWih_b, eWhh_b, ebih, ebhh, W1_b, b1, hroll, bl, cnt, flags);
  hipLaunchKernelGGL(dec_kernel, dim3(256), dim3(256), 92160, stream,
                     dWhh_b, dbih, dbhh, W2, b2, vt, vtb, bl, hroll, h0, X,
                     (float*)d_out, cnt, flags);
}

// Round 8
// 3541.848 us; speedup vs baseline: 1.6700x; 1.1257x over previous
//
#include <hip/hip_runtime.h>

#define NB 64      // batch
#define NL 512     // seq len
#define NT 64      // answer len
#define NH 512     // hidden
#define NE 256     // emb dim
#define NW 256     // attention weight dim
#define NBNH (NB * NH)
#define RS 16      // h-ring depth (slots); phase stamp = (t>>4)&1

typedef __attribute__((ext_vector_type(8))) short bf16x8;
typedef __attribute__((ext_vector_type(4))) float f32x4;
typedef unsigned short u16;
typedef unsigned int u32;
typedef unsigned long long u64;

#define STM 0x4000400040004000ull   // bit14 of each u16 (never set in bf16 of |v|<2)
#define CLRM 0xBFFFBFFFBFFFBFFFull

__device__ __forceinline__ float bf2f(u16 v){
  union { u32 u; float f; } x; x.u = ((u32)v) << 16; return x.f;
}
__device__ __forceinline__ u16 f2bf(float f){
  union { float f; u32 u; } x; x.f = f;
  return (u16)((x.u + 0x7FFFu + ((x.u >> 16) & 1u)) >> 16);
}
__device__ __forceinline__ float sigm(float x){ return 1.f / (1.f + __expf(-x)); }
__device__ __forceinline__ float tanh_(float x){ float e = __expf(2.f * x); return 1.f - 2.f / (e + 1.f); }

// agent-scope load: bypasses L1 (reads at/through the coherence point)
__device__ __forceinline__ u64 ald64(const u64* p){
  return __hip_atomic_load(p, __ATOMIC_RELAXED, __HIP_MEMORY_SCOPE_AGENT);
}
__device__ __forceinline__ u32 ald32(const u32* p){
  return __hip_atomic_load(p, __ATOMIC_RELAXED, __HIP_MEMORY_SCOPE_AGENT);
}
// agent-scope store: pushes to the device coherence point (cross-XCD safe)
__device__ __forceinline__ void ast64(u64* p, u64 v){
  __hip_atomic_store(p, v, __ATOMIC_RELAXED, __HIP_MEMORY_SCOPE_AGENT);
}
__device__ __forceinline__ void ast32(u32* p, u32 v){
  __hip_atomic_store(p, v, __ATOMIC_RELAXED, __HIP_MEMORY_SCOPE_AGENT);
}
// workgroup-scope store: plain store, write-through L1 -> LOCAL L2 only
__device__ __forceinline__ void st64(u64* p, u64 v){
  __hip_atomic_store(p, v, __ATOMIC_RELAXED, __HIP_MEMORY_SCOPE_WORKGROUP);
}
__device__ __forceinline__ void st32(u32* p, u32 v){
  __hip_atomic_store(p, v, __ATOMIC_RELAXED, __HIP_MEMORY_SCOPE_WORKGROUP);
}
// drain all outstanding vector-memory ops (forces stores to be accepted at
// the coherence point BEFORE anything after this line issues). R7 theory:
// without this, the flag doorbell races / the data lingers pre-L2 and
// consumers spin ~30 poll iterations per step.
__device__ __forceinline__ void vm_drain(){
  asm volatile("s_waitcnt vmcnt(0)" ::: "memory");
}
__device__ __forceinline__ bf16x8 mk8(u64 a, u64 b){
  union { u64 q[2]; bf16x8 v; } u; u.q[0] = a; u.q[1] = b; return u.v;
}
__device__ __forceinline__ u32 xcc_id(){
  u32 x;
  asm volatile("s_getreg_b32 %0, hwreg(HW_REG_XCC_ID)" : "=s"(x));
  return x & 7u;
}
// MFMA burn while polling (R4: neutral on enc recurrence, kept for dec
// workers / idle CUs; zero memory traffic)
__device__ __forceinline__ void burn32(f32x4* bacc, bf16x8 junk){
#pragma unroll
  for(int i = 0; i < 8; ++i)
#pragma unroll
    for(int g = 0; g < 4; ++g)
      bacc[g] = __builtin_amdgcn_mfma_f32_16x16x32_bf16(junk, junk, bacc[g], 0, 0, 0);
}
__device__ __forceinline__ void burn_sink(f32x4* bacc){
  asm volatile("" :: "v"(bacc[0][0]), "v"(bacc[1][0]), "v"(bacc[2][0]), "v"(bacc[3][0]));
}

__global__ void fill_kernel(u32* p, u32 v){
  p[blockIdx.x * 256 + threadIdx.x] = v;
}

// fp32 -> bf16 (round-to-nearest-even)
__global__ void cvt_kernel(const float* __restrict__ src, u16* __restrict__ dst, int n){
  const int i = blockIdx.x * 256 + threadIdx.x;
  if(i < n) dst[i] = f2bf(src[i]);
}

// ---------------------------------------------------------------------------
// Encoder, K-SPLIT + FLAG DOORBELL + BURN-ON-IDLE + STORE FENCE: identical to
// R4 except one line — s_waitcnt vmcnt(0) between the ring data stores and
// the flag doorbell. R4 post-mortem: per-step 5.14 us at full clock (MfmaUtil
// 60%) => DVFS dead; producer VALUBusy ~80% => ~30 spin iterations/step =>
// store->visibility lag is the live suspect.
// ---------------------------------------------------------------------------
__global__ void __launch_bounds__(256, 1) enc_kernel(
    const int* __restrict__ ids, const u16* __restrict__ emb,
    const u16* __restrict__ Wih, const u16* __restrict__ Whh,
    const float* __restrict__ bih, const float* __restrict__ bhh,
    const u16* __restrict__ W1,  const float* __restrict__ b1,
    u16* hroll, u16* bl, u32* cnt, u32* flags)
{
  extern __shared__ char dynsm[];         // 90 KB reserved (1 block/CU forcing)
  f32x4* pacc = (f32x4*)dynsm;            // [2 buf][2 pair][4 gate][64 lane]
  __shared__ u32 srank;

  const int lane = threadIdx.x & 63;
  const int wvl  = threadIdx.x >> 6;      // 0..3
  const int col  = lane & 15;
  const int quad = lane >> 4;

  const u32 xcd = xcc_id();
  if(xcd >= 4){
    // ---------------- burner: keep the clock domain hot ----------------
    f32x4 bacc[4];
#pragma unroll
    for(int g = 0; g < 4; ++g) bacc[g] = (f32x4){0.f, 0.f, 0.f, 0.f};
    const bf16x8 junk = {0, 0, 0, 0, 0, 0, 0, 0};
    const u32* dp = cnt + 64 + (xcd & 3);
    for(;;){
      if(ald32(dp) != 0u) break;
      burn32(bacc, junk); burn32(bacc, junk);
      burn32(bacc, junk); burn32(bacc, junk);
    }
    burn_sink(bacc);
    return;
  }
  if(threadIdx.x == 0) srank = atomicAdd(&cnt[xcd], 1u);
  __syncthreads();
  const u32 rank = srank;
  const int btile = (int)xcd;
  u32* fbase = flags + (size_t)xcd * (RS * 32);   // [slot][mtile]

  if(rank >= 16){
    if(rank >= 32) return;
    f32x4 bacc[4];
#pragma unroll
    for(int g = 0; g < 4; ++g) bacc[g] = (f32x4){0.f, 0.f, 0.f, 0.f};
    const bf16x8 junk = {0, 0, 0, 0, 0, 0, 0, 0};
    if(wvl != 0){
      // extra worker waves: burn until this XCD's producers finish
      const u32* dp = cnt + 64 + xcd;
      for(;;){
        if(ald32(dp) != 0u) break;
        burn32(bacc, junk); burn32(bacc, junk);
        burn32(bacc, junk); burn32(bacc, junk);
      }
      burn_sink(bacc);
      return;
    }
    // ---------------- blend1 worker: cols [ (rank-16)*16, +16 ) ----------------
    const int n1 = ((int)rank - 16) * 16 + col;
    bf16x8 w1f[16];                       // W1 row n1, register-cached
    const u16* w1p = W1 + (size_t)n1 * NH + quad * 8;
#pragma unroll
    for(int i = 0; i < 16; ++i) w1f[i] = *(const bf16x8*)(w1p + 32 * i);
    const float b1f = b1[n1];
    const int arow = btile * 16 + col;    // h row this lane holds as A-frag

    for(int t = 0; t < NL; ++t){
      const int slot = t & (RS - 1);
      const u32 fwant = (u32)((t >> 4) & 1);
      // flag poll: all 32 mtiles of this slot; burn between misses
      {
        const u32* fp = fbase + slot * 32;
        for(;;){
          const u32 f = ald32(fp + (lane & 31));
          if(__ballot(f == fwant) == ~0ull) break;
          burn32(bacc, junk);
        }
      }
      const u16* ha = hroll + (size_t)slot * NBNH + (size_t)arow * NH + quad * 8;
      const u64 want = fwant ? STM : 0ull;
      u64 hw[32];
      for(;;){                            // verify-once (flag raced data: rare)
        bool ok = true;
#pragma unroll
        for(int i = 0; i < 16; ++i){
          const u64* p = (const u64*)(ha + 32 * i);
          hw[2 * i]     = ald64(p);
          hw[2 * i + 1] = ald64(p + 1);
          ok = ok && ((hw[2 * i] & STM) == want) && ((hw[2 * i + 1] & STM) == want);
        }
        if(__ballot(ok) == ~0ull) break;
      }
      f32x4 a2 = {0.f, 0.f, 0.f, 0.f};
#pragma unroll
      for(int i = 0; i < 16; ++i)
        a2 = __builtin_amdgcn_mfma_f32_16x16x32_bf16(
               mk8(hw[2 * i] & CLRM, hw[2 * i + 1] & CLRM), w1f[i], a2, 0, 0, 0);
#pragma unroll
      for(int r = 0; r < 4; ++r){
        const int b = btile * 16 + quad * 4 + r;
        bl[((size_t)t * NB + b) * NW + n1] = f2bf(a2[r] + b1f);
      }
    }
    burn_sink(bacc);
    return;
  }

  // ------------------------------ producer ------------------------------
  const int mtile  = (int)rank * 2 + (wvl >> 1);   // 0..31
  const int khalf  = wvl & 1;                      // K-half of the recurrence
  const int pairid = wvl >> 1;                     // LDS pair slot
  const bool lowerw = (khalf == 0);
  const int j  = mtile * 16 + col;                 // hidden index within gate
  const int ab = btile * 16 + col;                 // A-row (batch) this lane loads

  float bias[4];
  const u16* wx[4];
  bf16x8 whr[8][4];                       // Whh fragments, THIS K-half only
#pragma unroll
  for(int g = 0; g < 4; ++g){
    const int row = g * NH + j;           // PyTorch gate order i,f,g,o
    bias[g] = bih[row] + bhh[row];
    wx[g] = Wih + (size_t)row * NE + khalf * 128 + quad * 8;
    const u16* whp = Whh + (size_t)row * NH + khalf * 256 + quad * 8;
#pragma unroll
    for(int i = 0; i < 8; ++i)
      whr[i][g] = *(const bf16x8*)(whp + 32 * i);
  }
  const int* idp = ids + ab * NL;         // ids is [B, L]
  float creg[4] = {0.f, 0.f, 0.f, 0.f};   // cell state (lower wave only live)

  u64 hb[16];                             // h K-half fragment
  f32x4 acc[4];

  // x-part of t=0 (this wave's K-half of NE)
  {
    const u16* xr = emb + (size_t)idp[0] * NE + khalf * 128 + quad * 8;
#pragma unroll
    for(int g = 0; g < 4; ++g) acc[g] = (f32x4){0.f, 0.f, 0.f, 0.f};
#pragma unroll
    for(int k0 = 0; k0 < 128; k0 += 32){
      const bf16x8 af = *(const bf16x8*)(xr + k0);
#pragma unroll
      for(int g = 0; g < 4; ++g)
        acc[g] = __builtin_amdgcn_mfma_f32_16x16x32_bf16(af, *(const bf16x8*)(wx[g] + k0), acc[g], 0, 0, 0);
    }
  }

  for(int t = 0; t < NL; ++t){
    // h-part for step t (hb = K-half of h_{t-1}, polled last iteration)
    if(t > 0){
#pragma unroll
      for(int i = 0; i < 8; ++i){
        const bf16x8 af = mk8(hb[2 * i], hb[2 * i + 1]);
#pragma unroll
        for(int g = 0; g < 4; ++g)
          acc[g] = __builtin_amdgcn_mfma_f32_16x16x32_bf16(af, whr[i][g], acc[g], 0, 0, 0);
      }
    }
    // issue next-step emb loads NOW: latency hides under barrier+epilogue
    bf16x8 xa0, xa1, xa2, xa3;
    const u16* xr = (t + 1 < NL) ? (emb + (size_t)idp[t + 1] * NE + khalf * 128 + quad * 8) : emb;
    xa0 = *(const bf16x8*)(xr);
    xa1 = *(const bf16x8*)(xr + 32);
    xa2 = *(const bf16x8*)(xr + 64);
    xa3 = *(const bf16x8*)(xr + 96);

    const int slot = t & (RS - 1);
    const u32 fphase = (u32)((t >> 4) & 1);

    // K-half merge: upper writes partial acc; one barrier; lower sums + epilogue
    if(!lowerw){
#pragma unroll
      for(int g = 0; g < 4; ++g)
        pacc[(((t & 1) * 2 + pairid) * 4 + g) * 64 + lane] = acc[g];
    }
    __syncthreads();
    if(lowerw){
#pragma unroll
      for(int g = 0; g < 4; ++g){
        const f32x4 pa = pacc[(((t & 1) * 2 + pairid) * 4 + g) * 64 + lane];
        acc[g][0] += pa[0]; acc[g][1] += pa[1]; acc[g][2] += pa[2]; acc[g][3] += pa[3];
      }
      const u64 pst = fphase ? STM : 0ull;
      u16* ho = hroll + (size_t)slot * NBNH;
#pragma unroll
      for(int r = 0; r < 4; ++r){
        const float gi = acc[0][r] + bias[0];
        const float gf = acc[1][r] + bias[1];
        const float gg = acc[2][r] + bias[2];
        const float go = acc[3][r] + bias[3];
        creg[r] = sigm(gf) * creg[r] + sigm(gi) * tanh_(gg);
        const u32 raw  = (u32)f2bf(sigm(go) * tanh_(creg[r]));
        const u32 pair = raw | (((u32)__shfl_xor((int)raw, 1, 64)) << 16);
        const u32 hi   = (u32)__shfl_xor((int)pair, 2, 64);
        if((col & 3) == 0){
          const int row = btile * 16 + quad * 4 + r;
          st64((u64*)(ho + (size_t)row * NH + mtile * 16 + col),
               ((u64)pair | ((u64)hi << 32)) | pst);
        }
      }
      // R7 CHANGE: drain stores to the coherence point BEFORE the doorbell.
      vm_drain();
      // flag doorbell (advisory; data stamps remain the correctness gate)
      if(lane == 0) st32(fbase + slot * 32 + mtile, fphase);
    }
    if(t + 1 < NL){
      // x-part of t+1 from the pre-issued registers
#pragma unroll
      for(int g = 0; g < 4; ++g) acc[g] = (f32x4){0.f, 0.f, 0.f, 0.f};
#pragma unroll
      for(int g = 0; g < 4; ++g){
        acc[g] = __builtin_amdgcn_mfma_f32_16x16x32_bf16(xa0, *(const bf16x8*)(wx[g]),      acc[g], 0, 0, 0);
        acc[g] = __builtin_amdgcn_mfma_f32_16x16x32_bf16(xa1, *(const bf16x8*)(wx[g] + 32), acc[g], 0, 0, 0);
        acc[g] = __builtin_amdgcn_mfma_f32_16x16x32_bf16(xa2, *(const bf16x8*)(wx[g] + 64), acc[g], 0, 0, 0);
        acc[g] = __builtin_amdgcn_mfma_f32_16x16x32_bf16(xa3, *(const bf16x8*)(wx[g] + 96), acc[g], 0, 0, 0);
      }
      // flag poll: this K-half's 16 mtile flags (64 B / wave / iter)
      {
        const u32* fp = fbase + slot * 32 + khalf * 16;
        for(;;){
          const u32 f = ald32(fp + (lane & 15));
          if(__ballot(f == fphase) == ~0ull) break;
        }
      }
      // data load + stamp verify (single pass expected post-fence)
      {
        const u16* ha = hroll + (size_t)slot * NBNH + (size_t)ab * NH + khalf * 256 + quad * 8;
        const u64 want = fphase ? STM : 0ull;
        for(;;){
          bool ok = true;
#pragma unroll
          for(int i = 0; i < 8; ++i){
            const u64* p = (const u64*)(ha + 32 * i);
            hb[2 * i]     = ald64(p);
            hb[2 * i + 1] = ald64(p + 1);
            ok = ok && ((hb[2 * i] & STM) == want) && ((hb[2 * i + 1] & STM) == want);
          }
          if(__ballot(ok) == ~0ull) break;
        }
#pragma unroll
        for(int i = 0; i < 16; ++i) hb[i] &= CLRM;
      }
    }
  }
  // signal burners: this XCD's recurrence is done (agent scope, cross-XCD)
  if(rank == 0 && threadIdx.x == 0) ast32(cnt + 64 + (u32)xcd, 1u);
}

// ---------------------------------------------------------------------------
// Decoder, R1-TOPOLOGY REVERT with K-split producers: 256 blocks, 1/CU.
// R4 evidence: the R2 "pinned ring + mirror republish" dec ran ~18 us/step
// vs R1's direct-store ~6 us/step — the mirror hop was a regression. Now:
// blocks 0..63 = producers (btile = blk>>4, 2 mtiles x 2 K-halves per block,
// unpinned), agent-scope stores straight into 64 write-once stamped hdX
// slots (stamp is IN the data -> self-validating, no flags/fence needed);
// poll slot t-1 directly. Blocks 64..255 = 192 attention workers.
// c0 = enc h_511 (hroll slot 15, stamp masked); h_{-1} = fp32 h0.
// ---------------------------------------------------------------------------
__global__ void __launch_bounds__(256, 1) dec_kernel(
    const u16* __restrict__ Whh, const float* __restrict__ bih, const float* __restrict__ bhh,
    const float* __restrict__ W2, const float* __restrict__ b2,
    const float* __restrict__ vt, const float* __restrict__ vtb,
    const u16* __restrict__ bl,  const u16* __restrict__ hroll,
    const float* __restrict__ h0f,
    u16* hdX, float* __restrict__ out)
{
  extern __shared__ char dynsm[];
  f32x4* pacc = (f32x4*)dynsm;            // [2][2][4][64]
  __shared__ __align__(16) float h_f[NH];
  __shared__ __align__(16) float u_lds[NW];
  __shared__ __align__(16) float vt_lds[NW];
  __shared__ float red[8];

  const int tid  = threadIdx.x;
  const int lane = tid & 63;
  const int wvl  = tid >> 6;
  const int col  = lane & 15;
  const int quad = lane >> 4;

  if(blockIdx.x < 64){
    // ------------------------------ producer ------------------------------
    const int btile  = (int)blockIdx.x >> 4;
    const int rank   = (int)blockIdx.x & 15;
    const int mtile  = rank * 2 + (wvl >> 1);
    const int khalf  = wvl & 1;
    const int pairid = wvl >> 1;
    const bool lowerw = (khalf == 0);
    const int j  = mtile * 16 + col;
    const int ab = btile * 16 + col;

    float bias[4];
    bf16x8 whr[8][4];
#pragma unroll
    for(int g = 0; g < 4; ++g){
      const int row = g * NH + j;
      bias[g] = bih[row] + bhh[row];
      const u16* whp = Whh + (size_t)row * NH + khalf * 256 + quad * 8;
#pragma unroll
      for(int i = 0; i < 8; ++i)
        whr[i][g] = *(const bf16x8*)(whp + 32 * i);
    }
    float creg[4] = {0.f, 0.f, 0.f, 0.f};
    if(lowerw){
      // c0 = enc h_511 (hroll slot 15; stamp bits set -> mask)
#pragma unroll
      for(int r = 0; r < 4; ++r){
        const int ci = (btile * 16 + quad * 4 + r) * NH + j;
        creg[r] = bf2f((u16)(hroll[(size_t)15 * NBNH + ci] & 0xBFFFu));
      }
    }
    u64 hb[16];
    f32x4 acc[4];

    // t=0 h-part: h_{-1} = h0 (fp32), this wave's K-half
    {
      const float* hp = h0f + (size_t)ab * NH + khalf * 256 + quad * 8;
#pragma unroll
      for(int g = 0; g < 4; ++g) acc[g] = (f32x4){0.f, 0.f, 0.f, 0.f};
#pragma unroll
      for(int i = 0; i < 8; ++i){
        const f32x4 a0 = *(const f32x4*)(hp + 32 * i);
        const f32x4 a1 = *(const f32x4*)(hp + 32 * i + 4);
        bf16x8 af;
#pragma unroll
        for(int q = 0; q < 4; ++q){ af[q] = (short)f2bf(a0[q]); af[q + 4] = (short)f2bf(a1[q]); }
#pragma unroll
        for(int g = 0; g < 4; ++g)
          acc[g] = __builtin_amdgcn_mfma_f32_16x16x32_bf16(af, whr[i][g], acc[g], 0, 0, 0);
      }
    }

    for(int t = 0; t < NT; ++t){
      if(t > 0){
#pragma unroll
        for(int g = 0; g < 4; ++g) acc[g] = (f32x4){0.f, 0.f, 0.f, 0.f};
#pragma unroll
        for(int i = 0; i < 8; ++i){
          const bf16x8 af = mk8(hb[2 * i], hb[2 * i + 1]);
#pragma unroll
          for(int g = 0; g < 4; ++g)
            acc[g] = __builtin_amdgcn_mfma_f32_16x16x32_bf16(af, whr[i][g], acc[g], 0, 0, 0);
        }
      }
      if(!lowerw){
#pragma unroll
        for(int g = 0; g < 4; ++g)
          pacc[(((t & 1) * 2 + pairid) * 4 + g) * 64 + lane] = acc[g];
      }
      __syncthreads();
      if(lowerw){
#pragma unroll
        for(int g = 0; g < 4; ++g){
          const f32x4 pa = pacc[(((t & 1) * 2 + pairid) * 4 + g) * 64 + lane];
          acc[g][0] += pa[0]; acc[g][1] += pa[1]; acc[g][2] += pa[2]; acc[g][3] += pa[3];
        }
        // epilogue: h_t stamped -> write-once slot t (agent scope, direct)
        u16* hn = hdX + (size_t)t * NBNH;
#pragma unroll
        for(int r = 0; r < 4; ++r){
          const float gi = acc[0][r] + bias[0];
          const float gf = acc[1][r] + bias[1];
          const float gg = acc[2][r] + bias[2];
          const float go = acc[3][r] + bias[3];
          creg[r] = sigm(gf) * creg[r] + sigm(gi) * tanh_(gg);
          const u32 stv  = (u32)f2bf(sigm(go) * tanh_(creg[r])) | 0x4000u;
          const u32 pair = stv | (((u32)__shfl_xor((int)stv, 1, 64)) << 16);
          const u32 hi   = (u32)__shfl_xor((int)pair, 2, 64);
          if((col & 3) == 0){
            const int row = btile * 16 + quad * 4 + r;
            ast64((u64*)(hn + (size_t)row * NH + mtile * 16 + col),
                  (u64)pair | ((u64)hi << 32));
          }
        }
      }
      if(t + 1 < NT){
        // poll slot t directly (write-once, stamp in data, no flags)
        const u16* ha = hdX + (size_t)t * NBNH + (size_t)ab * NH + khalf * 256 + quad * 8;
        for(;;){
          bool ok = true;
#pragma unroll
          for(int i = 0; i < 8; ++i){
            const u64* p = (const u64*)(ha + 32 * i);
            hb[2 * i]     = ald64(p);
            hb[2 * i + 1] = ald64(p + 1);
            ok = ok && ((hb[2 * i] & STM) == STM) && ((hb[2 * i + 1] & STM) == STM);
          }
          if(__ballot(ok) == ~0ull) break;
        }
#pragma unroll
        for(int i = 0; i < 16; ++i) hb[i] &= CLRM;
      }
    }
    return;
  }

  // ------------------------- attention worker path -------------------------
  const int wid = (int)blockIdx.x - 64;   // 0..191

  vt_lds[tid] = vt[tid];
  const float vtbf = vtb[0];
  __syncthreads();

  f32x4 bacc[4];
#pragma unroll
  for(int g = 0; g < 4; ++g) bacc[g] = (f32x4){0.f, 0.f, 0.f, 0.f};
  const bf16x8 junk = {0, 0, 0, 0, 0, 0, 0, 0};

  for(int tk = wid; tk < NT * NB; tk += 192){
    const int t = tk >> 6;
    const int b = tk & 63;

    // poll slot t row b (stamped bf16), stage -> fp32 LDS (burn-throttled)
    {
      const u32* hp = (const u32*)(hdX + (size_t)t * NBNH + (size_t)b * NH);
      u32 v;
      for(;;){
        v = ald32(hp + tid);
        burn32(bacc, junk);
        const int ok = ((v & 0x40004000u) == 0x40004000u) ? 1 : 0;
        if(__syncthreads_and(ok)) break;
      }
      h_f[2 * tid]     = bf2f((u16)(v & 0xBFFFu));
      h_f[2 * tid + 1] = bf2f((u16)((v >> 16) & 0xBFFFu));
    }
    __syncthreads();

    // u[n] = b2[n] + h . W2[n,:]   (h broadcast from LDS, f32x4 loads)
    {
      const float* w2r = W2 + (size_t)tid * NH;
      float s = b2[tid];
#pragma unroll 4
      for(int k = 0; k < NH; k += 4){
        const f32x4 hv = *(const f32x4*)(&h_f[k]);
        const f32x4 wv = *(const f32x4*)(w2r + k);
        s += hv[0] * wv[0] + hv[1] * wv[1] + hv[2] * wv[2] + hv[3] * wv[3];
      }
      u_lds[tid] = s;
    }
    __syncthreads();

    // scores for l = tid and l = tid+256 (bf16x8 row loads)
    float a0, a1;
#pragma unroll
    for(int e = 0; e < 2; ++e){
      const int l = tid + e * 256;
      const u16* br = bl + (size_t)(l * NB + b) * NW;
      float p = 0.f;
#pragma unroll 2
      for(int w0 = 0; w0 < NW; w0 += 8){
        const bf16x8 bv = *(const bf16x8*)(br + w0);
#pragma unroll
        for(int q = 0; q < 8; ++q)
          p += vt_lds[w0 + q] * tanh_(bf2f((u16)bv[q]) + u_lds[w0 + q]);
      }
      if(e == 0) a0 = p + vtbf; else a1 = p + vtbf;
    }

    // log-softmax over L = 512 (2 values per thread, block-wide reduction)
    float mx = fmaxf(a0, a1);
#pragma unroll
    for(int off = 32; off > 0; off >>= 1) mx = fmaxf(mx, __shfl_xor(mx, off, 64));
    if(lane == 0) red[wvl] = mx;
    __syncthreads();
    mx = fmaxf(fmaxf(red[0], red[1]), fmaxf(red[2], red[3]));
    float es = __expf(a0 - mx) + __expf(a1 - mx);
#pragma unroll
    for(int off = 32; off > 0; off >>= 1) es += __shfl_xor(es, off, 64);
    if(lane == 0) red[4 + wvl] = es;
    __syncthreads();
    const float lse = mx + logf(red[4] + red[5] + red[6] + red[7]);
    out[((size_t)tid * NB + b) * NT + t]         = a0 - lse;
    out[((size_t)(tid + 256) * NB + b) * NT + t] = a1 - lse;
    __syncthreads();
  }
  burn_sink(bacc);
}

// ---------------------------------------------------------------------------
extern "C" void kernel_launch(void* const* d_in, const int* in_sizes, int n_in,
                              void* d_out, int out_size, void* d_ws, size_t ws_size,
                              hipStream_t stream)
{
  (void)in_sizes; (void)n_in; (void)out_size; (void)ws_size;
  const int*   ids  = (const int*)d_in[0];
  const float* emb  = (const float*)d_in[1];
  const float* eWih = (const float*)d_in[2];
  const float* eWhh = (const float*)d_in[3];
  const float* ebih = (const float*)d_in[4];
  const float* ebhh = (const float*)d_in[5];
  /* d_in[6] = dec_Wih: unused (decoder input is identically zero) */
  const float* dWhh = (const float*)d_in[7];
  const float* dbih = (const float*)d_in[8];
  const float* dbhh = (const float*)d_in[9];
  const float* W1   = (const float*)d_in[10];
  const float* b1   = (const float*)d_in[11];
  const float* W2   = (const float*)d_in[12];
  const float* b2   = (const float*)d_in[13];
  const float* vt   = (const float*)d_in[14];
  const float* vtb  = (const float*)d_in[15];
  const float* h0   = (const float*)d_in[16];

  // workspace ~28.5 MB. X = bf16 emb during enc, then dec's 64 write-once h
  // slots (hdX; stale emb bf16 has bit14 clear for |v|<2 -> stamps valid
  // without pre-zeroing; 64*NBNH*2 = 4 MB <= 5.12 MB region). hroll = enc's
  // 16-deep local-L2 h ring (slot 15 = h_511 feeds dec c0). flags = enc
  // doorbells. cnt[64..67] = per-XCD enc-done flags (burner exit).
  char* ws = (char*)d_ws;
  u16* bl     = (u16*)ws; ws += (size_t)NL * NB * NW * 2;    // blend1 bf16  16.78 MB
  u16* hroll  = (u16*)ws; ws += (size_t)RS * NBNH * 2;       // h ring       1.05 MB
  u16* X      = (u16*)ws; ws += (size_t)10000 * NE * 2;      // emb_b / hdec 5.12 MB
  u16* eWih_b = (u16*)ws; ws += (size_t)4 * NH * NE * 2;     // 1.05 MB
  u16* eWhh_b = (u16*)ws; ws += (size_t)4 * NH * NH * 2;     // 2.10 MB
  u16* dWhh_b = (u16*)ws; ws += (size_t)4 * NH * NH * 2;     // 2.10 MB
  u16* W1_b   = (u16*)ws; ws += (size_t)NW * NH * 2;         // 0.26 MB
  u32* cnt    = (u32*)ws; ws += 1024;                        // rank/done counters
  u32* flags  = (u32*)ws; ws += (size_t)4 * RS * 32 * 4;     // doorbells 8 KB

  // ring + flags pre-filled with phase-1 pattern; counters zeroed
  hipLaunchKernelGGL(fill_kernel, dim3((RS * NBNH / 2) / 256), dim3(256), 0, stream,
                     (u32*)hroll, 0x40004000u);
  hipLaunchKernelGGL(fill_kernel, dim3(8), dim3(256), 0, stream, flags, 1u);
  hipLaunchKernelGGL(fill_kernel, dim3(1), dim3(256), 0, stream, cnt, 0u);
  hipLaunchKernelGGL(cvt_kernel, dim3(10000), dim3(256), 0, stream, emb,  X,      10000 * NE);
  hipLaunchKernelGGL(cvt_kernel, dim3(2048),  dim3(256), 0, stream, eWih, eWih_b, 4 * NH * NE);
  hipLaunchKernelGGL(cvt_kernel, dim3(4096),  dim3(256), 0, stream, eWhh, eWhh_b, 4 * NH * NH);
  hipLaunchKernelGGL(cvt_kernel, dim3(4096),  dim3(256), 0, stream, dWhh, dWhh_b, 4 * NH * NH);
  hipLaunchKernelGGL(cvt_kernel, dim3(512),   dim3(256), 0, stream, W1,   W1_b,   NW * NH);

  // 90 KB dynamic LDS -> 1 block/CU -> 256-block grid is a bijection onto
  // CUs (enc: XCD pigeonhole; dec: producer/worker isolation per CU)
  hipLaunchKernelGGL(enc_kernel, dim3(256), dim3(256), 92160, stream,
                     ids, X, eWih_b, eWhh_b, ebih, ebhh, W1_b, b1, hroll, bl, cnt, flags);
  hipLaunchKernelGGL(dec_kernel, dim3(256), dim3(256), 92160, stream,
                     dWhh_b, dbih, dbhh, W2, b2, vt, vtb, bl, hroll, h0, X,
                     (float*)d_out);
}